// Round 3
// baseline (550.892 us; speedup 1.0000x reference)
//
#include <hip/hip_runtime.h>

#define N_NODES 65536
#define N_EDGES 1048576
#define NB      512

typedef unsigned short u16;
typedef unsigned int   u32;
typedef unsigned long long u64;

typedef __attribute__((ext_vector_type(8))) short bf16x8;
typedef __attribute__((ext_vector_type(4))) float f32x4;

__device__ __forceinline__ float bf2f(u16 u) { return __uint_as_float(((u32)u) << 16); }
__device__ __forceinline__ float lo16(u32 u) { return __uint_as_float(u << 16); }
__device__ __forceinline__ float hi16(u32 u) { return __uint_as_float(u & 0xffff0000u); }
__device__ __forceinline__ u16 f2bf(float f) {
    u32 u = __float_as_uint(f);
    u32 r = (u + 0x7fffu + ((u >> 16) & 1u)) >> 16;
    return (u16)r;
}
__device__ __forceinline__ u32 pk2(float a, float b) {
    return (u32)f2bf(a) | ((u32)f2bf(b) << 16);
}
__device__ __forceinline__ float wsum(float v) {
    for (int o = 32; o; o >>= 1) v += __shfl_xor(v, o, 64);
    return v;
}
__device__ __forceinline__ float wmax(float v) {
    for (int o = 32; o; o >>= 1) v = fmaxf(v, __shfl_xor(v, o, 64));
    return v;
}

// ---------- tiny precompute ----------
__global__ void k_prep(const float* g1We, const float* g1ae, const float* g2We, const float* g2ae,
                       float* M1, float* M2) {
    int t = threadIdx.x;
    if (t < 20) {
        int j = t >> 2, h = t & 3;
        float s = 0.f;
        for (int c = 0; c < 64; c++) s += g1We[j * 256 + h * 64 + c] * g1ae[h * 64 + c];
        M1[t] = s;
    } else if (t < 25) {
        int j = t - 20;
        float s = 0.f;
        for (int c = 0; c < 64; c++) s += g2We[j * 64 + c] * g2ae[c];
        M2[j] = s;
    }
}

// ---------- weight transpose+bf16: g1Wt[c][k'] with k' 0..63=vis(13+k'), 64..76=x(k'-64), 77..127=0
__global__ void k_wt1(const float* __restrict__ g1W, u16* __restrict__ Wt) {
    int c = blockIdx.x;      // 0..255
    int k = threadIdx.x;     // 0..127
    float v = 0.f;
    if (k < 77) {
        int ko = (k < 64) ? (13 + k) : (k - 64);
        v = g1W[(size_t)ko * 256 + c];
    }
    Wt[(size_t)c * 128 + k] = f2bf(v);
}

// ---------- v1s[h][k] = sum_cc Wt[h*64+cc][k] * att_src[h][cc]  (feat-space attention vectors)
__global__ void k_prepv(const u16* __restrict__ Wt, const float* __restrict__ as_,
                        const float* __restrict__ ad_, float* __restrict__ v1s,
                        float* __restrict__ v1d) {
    int t = threadIdx.x;    // 0..511
    int h = t >> 7, k = t & 127;
    float s = 0.f, d = 0.f;
    for (int cc = 0; cc < 64; cc++) {
        float wv_ = bf2f(Wt[(size_t)(h * 64 + cc) * 128 + k]);
        s += wv_ * as_[h * 64 + cc];
        d += wv_ * ad_[h * 64 + cc];
    }
    v1s[t] = s;
    v1d[t] = d;
}

// ---------- Wt[c][k] = W[k][c] in bf16, c in [0,64), k in [0,256)  (roiW and g2W share this shape)
__global__ void k_wtv(const float* __restrict__ W, u16* __restrict__ Wt) {
    int c = blockIdx.x;      // 0..63
    int k = threadIdx.x;     // 0..255
    Wt[(size_t)c * 256 + k] = f2bf(W[(size_t)k * 64 + c]);
}

// ---------- scene ----------
__global__ __launch_bounds__(256) void k_scene(const float* __restrict__ gf, const float* __restrict__ W,
                                               const float* __restrict__ bias, float* __restrict__ scene) {
    int idx = blockIdx.x * 256 + threadIdx.x;
    int b = idx >> 7, j = idx & 127;
    float acc = 0.f;
    for (int k = 0; k < 512; k++) acc += gf[b * 512 + k] * W[k * 128 + j];
    scene[idx] = acc + bias[j];
}

// ---------- histogram ----------
__global__ __launch_bounds__(256) void k_hist(const int* ei, int* cnt) {
    int e = blockIdx.x * 256 + threadIdx.x;
    atomicAdd(&cnt[ei[N_EDGES + e]], 1);
}

// ---------- hierarchical exclusive scan ----------
__global__ __launch_bounds__(256) void k_scan_blk(const int* __restrict__ cnt, int* __restrict__ pre,
                                                  int* __restrict__ bsum) {
    __shared__ int sd[256];
    int t = threadIdx.x, b = blockIdx.x;
    int base = b * 1024 + t * 4;
    int4 c = *(const int4*)(cnt + base);
    int s = c.x + c.y + c.z + c.w;
    sd[t] = s;
    __syncthreads();
    for (int off = 1; off < 256; off <<= 1) {
        int v = (t >= off) ? sd[t - off] : 0;
        __syncthreads();
        sd[t] += v;
        __syncthreads();
    }
    int excl = sd[t] - s;
    int4 p;
    p.x = excl;
    p.y = excl + c.x;
    p.z = excl + c.x + c.y;
    p.w = excl + c.x + c.y + c.z;
    *(int4*)(pre + base) = p;
    if (t == 255) bsum[b] = sd[255];
}

__global__ __launch_bounds__(64) void k_scan_top(int* bsum) {
    int t = threadIdx.x;
    int v = bsum[t];
    int inc = v;
    for (int off = 1; off < 64; off <<= 1) {
        int u = __shfl_up(inc, off, 64);
        if (t >= off) inc += u;
    }
    bsum[t] = inc - v;
}

__global__ __launch_bounds__(256) void k_scan_fix(const int* __restrict__ pre, const int* __restrict__ bsum,
                                                  int* __restrict__ row_ptr, int* __restrict__ coarse_cur) {
    int i = blockIdx.x * 256 + threadIdx.x;
    int v = pre[i] + bsum[i >> 10];
    row_ptr[i] = v;
    if ((i & 255) == 0) coarse_cur[i >> 8] = v;
    if (i == 0) row_ptr[N_NODES] = N_EDGES;
}

// ---------- bucket pass ----------
__global__ __launch_bounds__(256) void k_bucket(const int* __restrict__ ei, int* coarse_cur,
                                                u32* __restrict__ bpack, int* __restrict__ bsrc) {
    __shared__ u32 stageP[4096];
    __shared__ int stageS[4096];
    __shared__ int bcnt[256], bscan[256], boff[256], gbase[256];
    int t = threadIdx.x;
    int e0 = blockIdx.x * 4096;
    bcnt[t] = 0;
    __syncthreads();
    int dreg[16], sreg[16];
    for (int it = 0; it < 16; it++) {
        int e = e0 + it * 256 + t;
        int dd = ei[N_EDGES + e];
        dreg[it] = dd;
        sreg[it] = ei[e];
        atomicAdd(&bcnt[dd >> 8], 1);
    }
    __syncthreads();
    int v = bcnt[t];
    bscan[t] = v;
    __syncthreads();
    for (int off = 1; off < 256; off <<= 1) {
        int u = (t >= off) ? bscan[t - off] : 0;
        __syncthreads();
        bscan[t] += u;
        __syncthreads();
    }
    boff[t] = bscan[t] - v;
    gbase[t] = v ? atomicAdd(&coarse_cur[t], v) : 0;
    __syncthreads();
    for (int it = 0; it < 16; it++) {
        int e = e0 + it * 256 + t;
        int b = dreg[it] >> 8;
        int pos = atomicAdd(&boff[b], 1);
        stageP[pos] = ((u32)e << 12) | (u32)(dreg[it] & 255);
        stageS[pos] = sreg[it];
    }
    __syncthreads();
    for (int idx = t; idx < 4096; idx += 256) {
        int lo = 0, hi = 255;
        while (lo < hi) { int mid = (lo + hi) >> 1; if (bscan[mid] > idx) hi = mid; else lo = mid + 1; }
        int b = lo;
        int g = gbase[b] + (idx - (bscan[b] - bcnt[b]));
        bpack[g] = stageP[idx];
        bsrc[g] = stageS[idx];
    }
}

// ---------- local sort within bucket ----------
__global__ __launch_bounds__(256) void k_sortb(const u32* __restrict__ bpack, const int* __restrict__ bsrc,
                                               const int* __restrict__ row_ptr,
                                               int* __restrict__ eord, int* __restrict__ ssrc) {
    __shared__ int cur[256];
    int t = threadIdx.x, b = blockIdx.x;
    int nbase = b * 256;
    cur[t] = row_ptr[nbase + t];
    __syncthreads();
    int beg = row_ptr[nbase];
    int end = row_ptr[nbase + 256];
    for (int i = beg + t; i < end; i += 256) {
        u32 wd = bpack[i];
        int src = bsrc[i];
        int d8 = wd & 255;
        int pos = atomicAdd(&cur[d8], 1);
        eord[pos] = (int)(wd >> 12);
        ssrc[pos] = src;
    }
}

// ---------- payload in pos order ----------
__global__ __launch_bounds__(256) void k_payload(const int* __restrict__ eord, const float* __restrict__ ea,
                                                 const float* __restrict__ M1, const float* __restrict__ M2,
                                                 float* __restrict__ a1es, float* __restrict__ a2es) {
    int pos = blockIdx.x * 256 + threadIdx.x;
    int e = eord[pos];
    float v[5];
    for (int j = 0; j < 5; j++) v[j] = ea[(size_t)e * 5 + j];
    float4 o;
    o.x = v[0]*M1[0]  + v[1]*M1[4]  + v[2]*M1[8]  + v[3]*M1[12] + v[4]*M1[16];
    o.y = v[0]*M1[1]  + v[1]*M1[5]  + v[2]*M1[9]  + v[3]*M1[13] + v[4]*M1[17];
    o.z = v[0]*M1[2]  + v[1]*M1[6]  + v[2]*M1[10] + v[3]*M1[14] + v[4]*M1[18];
    o.w = v[0]*M1[3]  + v[1]*M1[7]  + v[2]*M1[11] + v[3]*M1[15] + v[4]*M1[19];
    *(float4*)(a1es + (size_t)pos * 4) = o;
    a2es[pos] = v[0]*M2[0] + v[1]*M2[1] + v[2]*M2[2] + v[3]*M2[3] + v[4]*M2[4];
}

// ---------- featb[n][0..63] = relu(roi @ roiW + b) via MFMA; [64..76]=x(bf16); [77..127]=0 ----------
__global__ __launch_bounds__(256) void k_vis(const float* __restrict__ roi, const u16* __restrict__ Wt,
                                             const float* __restrict__ bias, const float* __restrict__ x,
                                             u16* __restrict__ featb) {
    __shared__ u16 At[64][264];
    int t = threadIdx.x;
    int w = t >> 6, l = t & 63, lo = l & 15, hi = l >> 4;
    int n0 = blockIdx.x * 64;
    int r = t >> 2, sub = t & 3;
    const float* rp = roi + (size_t)(n0 + r) * 256 + sub * 4;
    #pragma unroll
    for (int q = 0; q < 16; q++) {
        float4 v = *(const float4*)(rp + q * 16);
        uint2 p;
        p.x = pk2(v.x, v.y);
        p.y = pk2(v.z, v.w);
        *(uint2*)&At[r][q * 16 + sub * 4] = p;
    }
    {   // x part + zero pad
        u16* fb = featb + (size_t)(n0 + r) * 128;
        if (sub == 0) {
            const float* xp = x + (size_t)(n0 + r) * 13;
            #pragma unroll
            for (int j = 0; j < 13; j++) fb[64 + j] = f2bf(xp[j]);
        } else {
            int j0 = 77 + (sub - 1) * 17;
            #pragma unroll
            for (int j = 0; j < 17; j++) fb[j0 + j] = 0;
        }
    }
    float bb[4][4];
    #pragma unroll
    for (int cb = 0; cb < 4; cb++)
        #pragma unroll
        for (int rg = 0; rg < 4; rg++) bb[cb][rg] = bias[cb * 16 + hi * 4 + rg];
    __syncthreads();
    f32x4 acc[4];
    #pragma unroll
    for (int cb = 0; cb < 4; cb++) acc[cb] = (f32x4){0.f, 0.f, 0.f, 0.f};
    #pragma unroll
    for (int ks = 0; ks < 8; ks++) {
        bf16x8 af = *(const bf16x8*)(&At[w * 16 + lo][ks * 32 + hi * 8]);
        #pragma unroll
        for (int cb = 0; cb < 4; cb++) {
            bf16x8 wf = *(const bf16x8*)(Wt + (size_t)(cb * 16 + lo) * 256 + ks * 32 + hi * 8);
            acc[cb] = __builtin_amdgcn_mfma_f32_16x16x32_bf16(wf, af, acc[cb], 0, 0, 0);
        }
    }
    int nrow = n0 + w * 16 + lo;
    #pragma unroll
    for (int cb = 0; cb < 4; cb++) {
        uint2 p;
        p.x = pk2(fmaxf(acc[cb][0] + bb[cb][0], 0.f), fmaxf(acc[cb][1] + bb[cb][1], 0.f));
        p.y = pk2(fmaxf(acc[cb][2] + bb[cb][2], 0.f), fmaxf(acc[cb][3] + bb[cb][3], 0.f));
        *(uint2*)(featb + (size_t)nrow * 128 + cb * 16 + hi * 4) = p;
    }
}

// ---------- a1s/a1d[n][h] = featb[n] . v1{s,d}[h] ----------
__global__ __launch_bounds__(256) void k_a1(const u16* __restrict__ featb, const float* __restrict__ v1s,
                                            const float* __restrict__ v1d,
                                            float* __restrict__ a1s, float* __restrict__ a1d) {
    __shared__ float vs[512], vd[512];
    int t = threadIdx.x;
    for (int idx = t; idx < 512; idx += 256) { vs[idx] = v1s[idx]; vd[idx] = v1d[idx]; }
    __syncthreads();
    int n = blockIdx.x * 32 + (t >> 3), l8 = t & 7;
    const uint4* fp = (const uint4*)(featb + (size_t)n * 128 + l8 * 16);
    uint4 u0 = fp[0], u1 = fp[1];
    float f[16];
    f[0]=lo16(u0.x); f[1]=hi16(u0.x); f[2]=lo16(u0.y); f[3]=hi16(u0.y);
    f[4]=lo16(u0.z); f[5]=hi16(u0.z); f[6]=lo16(u0.w); f[7]=hi16(u0.w);
    f[8]=lo16(u1.x); f[9]=hi16(u1.x); f[10]=lo16(u1.y); f[11]=hi16(u1.y);
    f[12]=lo16(u1.z); f[13]=hi16(u1.z); f[14]=lo16(u1.w); f[15]=hi16(u1.w);
    float as4[4], ad4[4];
    #pragma unroll
    for (int h = 0; h < 4; h++) {
        float s = 0.f, d = 0.f;
        #pragma unroll
        for (int q = 0; q < 4; q++) {
            float4 v4 = *(const float4*)&vs[h * 128 + l8 * 16 + q * 4];
            float4 w4 = *(const float4*)&vd[h * 128 + l8 * 16 + q * 4];
            s += f[q*4+0]*v4.x + f[q*4+1]*v4.y + f[q*4+2]*v4.z + f[q*4+3]*v4.w;
            d += f[q*4+0]*w4.x + f[q*4+1]*w4.y + f[q*4+2]*w4.z + f[q*4+3]*w4.w;
        }
        as4[h] = s; ad4[h] = d;
    }
    #pragma unroll
    for (int h = 0; h < 4; h++) {
        for (int o = 1; o < 8; o <<= 1) {
            as4[h] += __shfl_xor(as4[h], o, 64);
            ad4[h] += __shfl_xor(ad4[h], o, 64);
        }
    }
    if (l8 == 0) {
        *(float4*)(a1s + (size_t)n * 4) = make_float4(as4[0], as4[1], as4[2], as4[3]);
        *(float4*)(a1d + (size_t)n * 4) = make_float4(ad4[0], ad4[1], ad4[2], ad4[3]);
    }
}

// ---------- GAT1 fused softmax + FEAT-space gather: one wave per node ----------
// phase1: logits -> per-wave LDS, online (m,s), rewrite LDS to normalized alpha
// phase2: G[n][h][128] = sum_e alpha[e][h] * featb[src_e]   (featb is L2/L3-resident)
__global__ __launch_bounds__(256) void k_sg1g(const int* __restrict__ row_ptr, const int* __restrict__ ssrc,
                                              const float* __restrict__ a1s, const float* __restrict__ a1d,
                                              const float* __restrict__ a1es, const u16* __restrict__ featb,
                                              u16* __restrict__ G) {
    __shared__ float wl[4][1024];   // per-wave: [edge<256][head<4]
    int t = threadIdx.x;
    int wv = t >> 6, L = t & 63;
    int n = blockIdx.x * 4 + wv;
    int beg = row_ptr[n], deg = row_ptr[n + 1] - beg;
    int lim = (deg < 256) ? deg : 256;
    {   // ---- phase 1 ----
        int h = L >> 4, j = L & 15;
        float adn = a1d[n * 4 + h];
        float m = -3.0e38f, s = 0.f;
        for (int i = j; i < deg; i += 16) {
            int pos = beg + i;
            float l = a1s[ssrc[pos] * 4 + h] + adn + a1es[(size_t)pos * 4 + h];
            l = (l > 0.f) ? l : 0.2f * l;
            if (i < 256) wl[wv][i * 4 + h] = l;
            if (l > m) { s = s * __expf(m - l) + 1.f; m = l; }
            else       { s += __expf(l - m); }
        }
        for (int o = 1; o < 16; o <<= 1) {
            float mo = __shfl_xor(m, o, 64), so = __shfl_xor(s, o, 64);
            float M = fmaxf(m, mo);
            s = s * __expf(m - M) + so * __expf(mo - M);
            m = M;
        }
        float inv = 1.f / (s + 1e-16f);
        for (int i = j; i < lim; i += 16)
            wl[wv][i * 4 + h] = __expf(wl[wv][i * 4 + h] - m) * inv;
    }
    __syncthreads();
    // ---- phase 2: 4 edges in parallel x 16 channel-group lanes ----
    int es = L >> 4;        // edge sub-slot 0..3
    int cg = L & 15;        // channel group: ch = cg*8 .. +7
    float acc[4][8];
    #pragma unroll
    for (int h = 0; h < 4; h++)
        #pragma unroll
        for (int j2 = 0; j2 < 8; j2++) acc[h][j2] = 0.f;
    for (int i = 0; i < deg; i += 4) {
        int ii = i + es;
        bool v = ii < deg;
        int pos = v ? beg + ii : beg;
        int s = ssrc[pos];
        float4 al = v ? *(const float4*)&wl[wv][ii * 4] : make_float4(0.f, 0.f, 0.f, 0.f);
        uint4 u = *((const uint4*)(featb + (size_t)s * 128) + cg);
        float f0 = lo16(u.x), f1 = hi16(u.x), f2 = lo16(u.y), f3 = hi16(u.y);
        float f4 = lo16(u.z), f5 = hi16(u.z), f6 = lo16(u.w), f7 = hi16(u.w);
        #pragma unroll
        for (int h = 0; h < 4; h++) {
            float a = (&al.x)[h];
            acc[h][0] += a * f0; acc[h][1] += a * f1;
            acc[h][2] += a * f2; acc[h][3] += a * f3;
            acc[h][4] += a * f4; acc[h][5] += a * f5;
            acc[h][6] += a * f6; acc[h][7] += a * f7;
        }
    }
    #pragma unroll
    for (int h = 0; h < 4; h++)
        #pragma unroll
        for (int j2 = 0; j2 < 8; j2++) {
            acc[h][j2] += __shfl_xor(acc[h][j2], 16, 64);
            acc[h][j2] += __shfl_xor(acc[h][j2], 32, 64);
        }
    if (es == 0) {
        #pragma unroll
        for (int h = 0; h < 4; h++) {
            uint4 p;
            p.x = pk2(acc[h][0], acc[h][1]);
            p.y = pk2(acc[h][2], acc[h][3]);
            p.z = pk2(acc[h][4], acc[h][5]);
            p.w = pk2(acc[h][6], acc[h][7]);
            *((uint4*)(G + ((size_t)n * 4 + h) * 128) + cg) = p;
        }
    }
}

// ---------- out1 = relu(G @ g1Wt + b) via MFMA, no LDS ----------
// wave w = head w; D[channel][node] transposed compute as in k_h2
__global__ __launch_bounds__(256) void k_go1(const u16* __restrict__ G, const u16* __restrict__ Wt,
                                             const float* __restrict__ bias, u16* __restrict__ out1) {
    int t = threadIdx.x;
    int w = t >> 6, l = t & 63, lo = l & 15, hi = l >> 4;
    int n0 = blockIdx.x * 64;
    bf16x8 wf[4][4];
    float bb[4][4];
    #pragma unroll
    for (int cb = 0; cb < 4; cb++) {
        #pragma unroll
        for (int ks = 0; ks < 4; ks++)
            wf[cb][ks] = *(const bf16x8*)(Wt + (size_t)(w * 64 + cb * 16 + lo) * 128 + ks * 32 + hi * 8);
        #pragma unroll
        for (int rg = 0; rg < 4; rg++)
            bb[cb][rg] = bias[w * 64 + cb * 16 + hi * 4 + rg];
    }
    #pragma unroll
    for (int nb = 0; nb < 4; nb++) {
        f32x4 acc[4];
        #pragma unroll
        for (int cb = 0; cb < 4; cb++) acc[cb] = (f32x4){0.f, 0.f, 0.f, 0.f};
        int nrow = n0 + nb * 16 + lo;
        const u16* gp = G + ((size_t)nrow * 4 + w) * 128 + hi * 8;
        #pragma unroll
        for (int ks = 0; ks < 4; ks++) {
            bf16x8 af = *(const bf16x8*)(gp + ks * 32);
            #pragma unroll
            for (int cb = 0; cb < 4; cb++)
                acc[cb] = __builtin_amdgcn_mfma_f32_16x16x32_bf16(wf[cb][ks], af, acc[cb], 0, 0, 0);
        }
        #pragma unroll
        for (int cb = 0; cb < 4; cb++) {
            uint2 p;
            p.x = pk2(fmaxf(acc[cb][0] + bb[cb][0], 0.f), fmaxf(acc[cb][1] + bb[cb][1], 0.f));
            p.y = pk2(fmaxf(acc[cb][2] + bb[cb][2], 0.f), fmaxf(acc[cb][3] + bb[cb][3], 0.f));
            *(uint2*)(out1 + (size_t)nrow * 256 + w * 64 + cb * 16 + hi * 4) = p;
        }
    }
}

// ---------- h2 = out1(bf16) @ g2Wt via MFMA, no LDS, fused a2s/a2d ----------
__global__ __launch_bounds__(256) void k_h2(const u16* __restrict__ A, const u16* __restrict__ Wt,
                                            const float* __restrict__ as_, const float* __restrict__ ad_,
                                            u16* __restrict__ out, float* __restrict__ a2s,
                                            float* __restrict__ a2d) {
    int t = threadIdx.x;
    int w = t >> 6, l = t & 63, lo = l & 15, hi = l >> 4;
    int nrow = blockIdx.x * 64 + w * 16 + lo;
    f32x4 acc[4];
    #pragma unroll
    for (int cb = 0; cb < 4; cb++) acc[cb] = (f32x4){0.f, 0.f, 0.f, 0.f};
    const u16* ap = A + (size_t)nrow * 256 + hi * 8;
    #pragma unroll
    for (int ks = 0; ks < 8; ks++) {
        bf16x8 af = *(const bf16x8*)(ap + ks * 32);
        #pragma unroll
        for (int cb = 0; cb < 4; cb++) {
            bf16x8 wf = *(const bf16x8*)(Wt + (size_t)(cb * 16 + lo) * 256 + ks * 32 + hi * 8);
            acc[cb] = __builtin_amdgcn_mfma_f32_16x16x32_bf16(wf, af, acc[cb], 0, 0, 0);
        }
    }
    float ps = 0.f, pd = 0.f;
    #pragma unroll
    for (int cb = 0; cb < 4; cb++) {
        uint2 p;
        p.x = pk2(acc[cb][0], acc[cb][1]);
        p.y = pk2(acc[cb][2], acc[cb][3]);
        *(uint2*)(out + (size_t)nrow * 64 + cb * 16 + hi * 4) = p;
        #pragma unroll
        for (int rg = 0; rg < 4; rg++) {
            float a = acc[cb][rg];
            ps += a * as_[cb * 16 + hi * 4 + rg];
            pd += a * ad_[cb * 16 + hi * 4 + rg];
        }
    }
    ps += __shfl_xor(ps, 16, 64); ps += __shfl_xor(ps, 32, 64);
    pd += __shfl_xor(pd, 16, 64); pd += __shfl_xor(pd, 32, 64);
    if (hi == 0) {
        a2s[nrow] = ps;
        a2d[nrow] = pd;
    }
}

// ---------- GAT2 fused softmax+gather: one wave per node ----------
__global__ __launch_bounds__(256) void k_sg2(const int* __restrict__ row_ptr, const int* __restrict__ ssrc,
                                             const float* __restrict__ a2s, const float* __restrict__ a2d,
                                             const float* __restrict__ a2es, const u16* __restrict__ h2b,
                                             const float* __restrict__ bias, float* __restrict__ hfin) {
    __shared__ float wl[4][256];
    int t = threadIdx.x;
    int wv = t >> 6, L = t & 63;
    int n = blockIdx.x * 4 + wv;
    int beg = row_ptr[n], deg = row_ptr[n + 1] - beg;
    int lim = (deg < 256) ? deg : 256;
    {   // ---- phase 1 ----
        float adn = a2d[n];
        float m = -3.0e38f, s = 0.f;
        for (int i = L; i < deg; i += 64) {
            int pos = beg + i;
            float l = a2s[ssrc[pos]] + adn + a2es[pos];
            l = (l > 0.f) ? l : 0.2f * l;
            if (i < 256) wl[wv][i] = l;
            if (l > m) { s = s * __expf(m - l) + 1.f; m = l; }
            else       { s += __expf(l - m); }
        }
        for (int o = 1; o < 64; o <<= 1) {
            float mo = __shfl_xor(m, o, 64), so = __shfl_xor(s, o, 64);
            float M = fmaxf(m, mo);
            s = s * __expf(m - M) + so * __expf(mo - M);
            m = M;
        }
        float inv = 1.f / (s + 1e-16f);
        for (int i = L; i < lim; i += 64)
            wl[wv][i] = __expf(wl[wv][i] - m) * inv;
    }
    __syncthreads();
    // ---- phase 2 ----
    int halfE = L >> 5;
    int L32 = L & 31;
    float a0 = 0.f, a1v = 0.f;
    int last = beg + deg - 1;
    const u32* h2u = (const u32*)h2b;
    for (int i = 0; i < deg; i += 8) {
        int iA = i + halfE, iB = i + 2 + halfE, iC = i + 4 + halfE, iD = i + 6 + halfE;
        bool vA = iA < deg, vB = iB < deg, vC = iC < deg, vD = iD < deg;
        int cA = vA ? beg + iA : last, cB = vB ? beg + iB : last;
        int cC = vC ? beg + iC : last, cD = vD ? beg + iD : last;
        int sA = ssrc[cA], sB = ssrc[cB], sC = ssrc[cC], sD = ssrc[cD];
        float wA = vA ? wl[wv][iA] : 0.f;
        float wB = vB ? wl[wv][iB] : 0.f;
        float wC = vC ? wl[wv][iC] : 0.f;
        float wD = vD ? wl[wv][iD] : 0.f;
        u32 uA = h2u[(size_t)sA * 32 + L32];
        u32 uB = h2u[(size_t)sB * 32 + L32];
        u32 uC = h2u[(size_t)sC * 32 + L32];
        u32 uD = h2u[(size_t)sD * 32 + L32];
        a0  += wA * lo16(uA) + wB * lo16(uB) + wC * lo16(uC) + wD * lo16(uD);
        a1v += wA * hi16(uA) + wB * hi16(uB) + wC * hi16(uC) + wD * hi16(uD);
    }
    a0  += __shfl_xor(a0, 32, 64);
    a1v += __shfl_xor(a1v, 32, 64);
    if (halfE == 0) {
        float2 o;
        o.x = a0  + bias[2 * L32];
        o.y = a1v + bias[2 * L32 + 1];
        *(float2*)(hfin + (size_t)n * 64 + 2 * L32) = o;
    }
}

// ---------- pooling + classifier ----------
__global__ __launch_bounds__(64) void k_pool(const int* __restrict__ bvec, const float* __restrict__ hf,
                                             const float* gateW, const float* gateb,
                                             const float* __restrict__ scene,
                                             const float* c1W, const float* c1b,
                                             const float* c2W, const float* c2b,
                                             float* __restrict__ outp) {
    int b = blockIdx.x, lane = threadIdx.x;
    __shared__ float gwl[64], se[64], comb[192], hid[64];
    gwl[lane] = gateW[lane];
    __syncthreads();
    int s0, s1;
    { int lo = 0, hi = N_NODES; while (lo < hi) { int mid = (lo + hi) >> 1; if (bvec[mid] < b) lo = mid + 1; else hi = mid; } s0 = lo; }
    { int lo = 0, hi = N_NODES; while (lo < hi) { int mid = (lo + hi) >> 1; if (bvec[mid] < b + 1) lo = mid + 1; else hi = mid; } s1 = lo; }
    float gb = gateb[0];
    float m = -3.0e38f, ssum = 0.f, acc = 0.f;
    for (int cs = s0; cs < s1; cs += 64) {
        int cnt = min(64, s1 - cs);
        float l = -3.0e38f;
        if (lane < cnt) {
            int n = cs + lane;
            float d = 0.f;
            for (int i = 0; i < 64; i++) d += hf[(size_t)n * 64 + i] * gwl[i];
            l = d + gb;
        }
        float cm = wmax(l);
        float newm = fmaxf(m, cm);
        float rsc = __expf(m - newm);
        float e = (lane < cnt) ? __expf(l - newm) : 0.f;
        float es = wsum(e);
        ssum = ssum * rsc + es;
        se[lane] = e;
        __syncthreads();
        float a2 = 0.f;
        for (int i = 0; i < cnt; i++) a2 += se[i] * hf[(size_t)(cs + i) * 64 + lane];
        acc = acc * rsc + a2;
        __syncthreads();
        m = newm;
    }
    float rel = acc / (ssum + 1e-16f);
    comb[lane] = scene[b * 128 + lane];
    comb[64 + lane] = scene[b * 128 + 64 + lane];
    comb[128 + lane] = rel;
    __syncthreads();
    float hj = 0.f;
    for (int k = 0; k < 192; k++) hj += comb[k] * c1W[k * 64 + lane];
    hj += c1b[lane];
    hid[lane] = fmaxf(hj, 0.f);
    __syncthreads();
    if (lane < 3) {
        float o = 0.f;
        for (int k = 0; k < 64; k++) o += hid[k] * c2W[k * 3 + lane];
        o += c2b[lane];
        outp[b * 3 + lane] = o;
    }
}

extern "C" void kernel_launch(void* const* d_in, const int* in_sizes, int n_in,
                              void* d_out, int out_size, void* d_ws, size_t ws_size,
                              hipStream_t stream) {
    (void)in_sizes; (void)n_in; (void)out_size; (void)ws_size;
    const float* gf     = (const float*)d_in[0];
    const float* x      = (const float*)d_in[1];
    const float* roi    = (const float*)d_in[2];
    const int*   ei     = (const int*)d_in[3];
    const float* ea     = (const float*)d_in[4];
    const int*   bvec   = (const int*)d_in[5];
    const float* roiW   = (const float*)d_in[6];
    const float* roib   = (const float*)d_in[7];
    const float* sceneW = (const float*)d_in[8];
    const float* sceneb = (const float*)d_in[9];
    const float* g1W    = (const float*)d_in[10];
    const float* g1as   = (const float*)d_in[11];
    const float* g1ad   = (const float*)d_in[12];
    const float* g1We   = (const float*)d_in[13];
    const float* g1ae   = (const float*)d_in[14];
    const float* g1b    = (const float*)d_in[15];
    const float* g2W    = (const float*)d_in[16];
    const float* g2as   = (const float*)d_in[17];
    const float* g2ad   = (const float*)d_in[18];
    const float* g2We   = (const float*)d_in[19];
    const float* g2ae   = (const float*)d_in[20];
    const float* g2b    = (const float*)d_in[21];
    const float* gateW  = (const float*)d_in[22];
    const float* gateb  = (const float*)d_in[23];
    const float* c1W    = (const float*)d_in[24];
    const float* c1b    = (const float*)d_in[25];
    const float* c2W    = (const float*)d_in[26];
    const float* c2b    = (const float*)d_in[27];

    char* w = (char*)d_ws;
    size_t o = 0;
    auto nxt = [&](size_t bytes) -> char* {
        char* p = w + o;
        o += (bytes + 255) & ~(size_t)255;
        return p;
    };
    float* scene  = (float*)nxt((size_t)NB * 128 * 4);
    float* M1     = (float*)nxt(80);
    float* M2     = (float*)nxt(32);
    u16* g1Wt     = (u16*)nxt((size_t)256 * 128 * 2);
    u16* roiWt    = (u16*)nxt((size_t)64 * 256 * 2);
    u16* g2Wt     = (u16*)nxt((size_t)64 * 256 * 2);
    float* v1s    = (float*)nxt(512 * 4);
    float* v1d    = (float*)nxt(512 * 4);
    int* cnt      = (int*)nxt((size_t)N_NODES * 4);
    int* pre      = (int*)nxt((size_t)N_NODES * 4);
    int* bsum     = (int*)nxt(64 * 4);
    int* row_ptr  = (int*)nxt((size_t)(N_NODES + 1) * 4);
    int* coarse   = (int*)nxt(256 * 4);
    u32* bpack    = (u32*)nxt((size_t)N_EDGES * 4);
    int* bsrc     = (int*)nxt((size_t)N_EDGES * 4);
    int* eord     = (int*)nxt((size_t)N_EDGES * 4);
    int* ssrc     = (int*)nxt((size_t)N_EDGES * 4);
    float* a1es   = (float*)nxt((size_t)N_EDGES * 16);
    float* a2es   = (float*)nxt((size_t)N_EDGES * 4);
    u16* featb    = (u16*)nxt((size_t)N_NODES * 128 * 2);
    u16* G        = (u16*)nxt((size_t)N_NODES * 4 * 128 * 2);
    u16* out1     = (u16*)nxt((size_t)N_NODES * 256 * 2);
    u16* h2b      = (u16*)nxt((size_t)N_NODES * 64 * 2);
    float* hfin   = (float*)nxt((size_t)N_NODES * 64 * 4);
    float* a1s    = (float*)nxt((size_t)N_NODES * 16);
    float* a1d    = (float*)nxt((size_t)N_NODES * 16);
    float* a2s    = (float*)nxt((size_t)N_NODES * 4);
    float* a2d    = (float*)nxt((size_t)N_NODES * 4);

    hipMemsetAsync(cnt, 0, (size_t)N_NODES * 4, stream);
    k_prep<<<1, 32, 0, stream>>>(g1We, g1ae, g2We, g2ae, M1, M2);
    k_wt1<<<256, 128, 0, stream>>>(g1W, g1Wt);
    k_prepv<<<1, 512, 0, stream>>>(g1Wt, g1as, g1ad, v1s, v1d);
    k_wtv<<<64, 256, 0, stream>>>(roiW, roiWt);
    k_wtv<<<64, 256, 0, stream>>>(g2W, g2Wt);
    k_scene<<<(NB * 128) / 256, 256, 0, stream>>>(gf, sceneW, sceneb, scene);
    k_hist<<<N_EDGES / 256, 256, 0, stream>>>(ei, cnt);
    k_scan_blk<<<64, 256, 0, stream>>>(cnt, pre, bsum);
    k_scan_top<<<1, 64, 0, stream>>>(bsum);
    k_scan_fix<<<N_NODES / 256, 256, 0, stream>>>(pre, bsum, row_ptr, coarse);
    k_bucket<<<256, 256, 0, stream>>>(ei, coarse, bpack, bsrc);
    k_sortb<<<256, 256, 0, stream>>>(bpack, bsrc, row_ptr, eord, ssrc);
    k_payload<<<N_EDGES / 256, 256, 0, stream>>>(eord, ea, M1, M2, a1es, a2es);
    k_vis<<<N_NODES / 64, 256, 0, stream>>>(roi, roiWt, roib, x, featb);
    k_a1<<<N_NODES / 32, 256, 0, stream>>>(featb, v1s, v1d, a1s, a1d);
    k_sg1g<<<N_NODES / 4, 256, 0, stream>>>(row_ptr, ssrc, a1s, a1d, a1es, featb, G);
    k_go1<<<N_NODES / 64, 256, 0, stream>>>(G, g1Wt, g1b, out1);
    k_h2<<<N_NODES / 64, 256, 0, stream>>>(out1, g2Wt, g2as, g2ad, h2b, a2s, a2d);
    k_sg2<<<N_NODES / 4, 256, 0, stream>>>(row_ptr, ssrc, a2s, a2d, a2es, h2b, g2b, hfin);
    k_pool<<<NB, 64, 0, stream>>>(bvec, hfin, gateW, gateb, scene, c1W, c1b, c2W, c2b, (float*)d_out);
}

// Round 4
// 544.027 us; speedup vs baseline: 1.0126x; 1.0126x over previous
//
#include <hip/hip_runtime.h>

#define N_NODES 65536
#define N_EDGES 1048576
#define NB      512

typedef unsigned short u16;
typedef unsigned int   u32;
typedef unsigned long long u64;

typedef __attribute__((ext_vector_type(8))) short bf16x8;
typedef __attribute__((ext_vector_type(4))) float f32x4;

__device__ __forceinline__ float bf2f(u16 u) { return __uint_as_float(((u32)u) << 16); }
__device__ __forceinline__ float lo16(u32 u) { return __uint_as_float(u << 16); }
__device__ __forceinline__ float hi16(u32 u) { return __uint_as_float(u & 0xffff0000u); }
__device__ __forceinline__ u16 f2bf(float f) {
    u32 u = __float_as_uint(f);
    u32 r = (u + 0x7fffu + ((u >> 16) & 1u)) >> 16;
    return (u16)r;
}
__device__ __forceinline__ u32 pk2(float a, float b) {
    return (u32)f2bf(a) | ((u32)f2bf(b) << 16);
}
__device__ __forceinline__ float wsum(float v) {
    for (int o = 32; o; o >>= 1) v += __shfl_xor(v, o, 64);
    return v;
}
__device__ __forceinline__ float wmax(float v) {
    for (int o = 32; o; o >>= 1) v = fmaxf(v, __shfl_xor(v, o, 64));
    return v;
}

// ---------- mega prep: all weight transposes + M1/M2 + v1s/v1d in one launch ----------
// blocks 0..63   : g1Wt[c][k']  (256 x 128, k' = vis-first reorder, bf16)
// blocks 64..95  : roiWt[c][k]  (64 x 256 bf16)
// blocks 96..127 : g2Wt[c][k]   (64 x 256 bf16)
// block 128      : v1s/v1d[h][k'] from fp32 g1W
// block 129      : M1 (20), M2 (5)
__global__ __launch_bounds__(512) void k_wprep(const float* __restrict__ g1W, const float* __restrict__ roiW,
                                               const float* __restrict__ g2W,
                                               const float* __restrict__ g1as, const float* __restrict__ g1ad,
                                               const float* __restrict__ g1We, const float* __restrict__ g1ae,
                                               const float* __restrict__ g2We, const float* __restrict__ g2ae,
                                               u16* __restrict__ g1Wt, u16* __restrict__ roiWt,
                                               u16* __restrict__ g2Wt, float* __restrict__ v1s,
                                               float* __restrict__ v1d, float* __restrict__ M1,
                                               float* __restrict__ M2) {
    int b = blockIdx.x, t = threadIdx.x;
    if (b < 64) {
        int c = b * 4 + (t >> 7), k = t & 127;
        float v = 0.f;
        if (k < 77) {
            int ko = (k < 64) ? (13 + k) : (k - 64);
            v = g1W[(size_t)ko * 256 + c];
        }
        g1Wt[(size_t)c * 128 + k] = f2bf(v);
    } else if (b < 96) {
        int c = (b - 64) * 2 + (t >> 8), k = t & 255;
        roiWt[(size_t)c * 256 + k] = f2bf(roiW[(size_t)k * 64 + c]);
    } else if (b < 128) {
        int c = (b - 96) * 2 + (t >> 8), k = t & 255;
        g2Wt[(size_t)c * 256 + k] = f2bf(g2W[(size_t)k * 64 + c]);
    } else if (b == 128) {
        int h = t >> 7, k = t & 127;
        float s = 0.f, d = 0.f;
        if (k < 77) {
            int ko = (k < 64) ? (13 + k) : (k - 64);
            for (int cc = 0; cc < 64; cc++) {
                float wv_ = g1W[(size_t)ko * 256 + h * 64 + cc];
                s += wv_ * g1as[h * 64 + cc];
                d += wv_ * g1ad[h * 64 + cc];
            }
        }
        v1s[t] = s;
        v1d[t] = d;
    } else {
        if (t < 20) {
            int j = t >> 2, h = t & 3;
            float s = 0.f;
            for (int c = 0; c < 64; c++) s += g1We[j * 256 + h * 64 + c] * g1ae[h * 64 + c];
            M1[t] = s;
        } else if (t < 25) {
            int j = t - 20;
            float s = 0.f;
            for (int c = 0; c < 64; c++) s += g2We[j * 64 + c] * g2ae[c];
            M2[j] = s;
        }
    }
}

// ---------- scene ----------
__global__ __launch_bounds__(256) void k_scene(const float* __restrict__ gf, const float* __restrict__ W,
                                               const float* __restrict__ bias, float* __restrict__ scene) {
    int idx = blockIdx.x * 256 + threadIdx.x;
    int b = idx >> 7, j = idx & 127;
    float acc = 0.f;
    for (int k = 0; k < 512; k++) acc += gf[b * 512 + k] * W[k * 128 + j];
    scene[idx] = acc + bias[j];
}

// ---------- histogram ----------
__global__ __launch_bounds__(256) void k_hist(const int* ei, int* cnt) {
    int e = blockIdx.x * 256 + threadIdx.x;
    atomicAdd(&cnt[ei[N_EDGES + e]], 1);
}

// ---------- hierarchical exclusive scan ----------
__global__ __launch_bounds__(256) void k_scan_blk(const int* __restrict__ cnt, int* __restrict__ pre,
                                                  int* __restrict__ bsum) {
    __shared__ int sd[256];
    int t = threadIdx.x, b = blockIdx.x;
    int base = b * 1024 + t * 4;
    int4 c = *(const int4*)(cnt + base);
    int s = c.x + c.y + c.z + c.w;
    sd[t] = s;
    __syncthreads();
    for (int off = 1; off < 256; off <<= 1) {
        int v = (t >= off) ? sd[t - off] : 0;
        __syncthreads();
        sd[t] += v;
        __syncthreads();
    }
    int excl = sd[t] - s;
    int4 p;
    p.x = excl;
    p.y = excl + c.x;
    p.z = excl + c.x + c.y;
    p.w = excl + c.x + c.y + c.z;
    *(int4*)(pre + base) = p;
    if (t == 255) bsum[b] = sd[255];
}

__global__ __launch_bounds__(64) void k_scan_top(int* bsum) {
    int t = threadIdx.x;
    int v = bsum[t];
    int inc = v;
    for (int off = 1; off < 64; off <<= 1) {
        int u = __shfl_up(inc, off, 64);
        if (t >= off) inc += u;
    }
    bsum[t] = inc - v;
}

__global__ __launch_bounds__(256) void k_scan_fix(const int* __restrict__ pre, const int* __restrict__ bsum,
                                                  int* __restrict__ row_ptr, int* __restrict__ coarse_cur) {
    int i = blockIdx.x * 256 + threadIdx.x;
    int v = pre[i] + bsum[i >> 10];
    row_ptr[i] = v;
    if ((i & 255) == 0) coarse_cur[i >> 8] = v;
    if (i == 0) row_ptr[N_NODES] = N_EDGES;
}

// ---------- bucket pass ----------
__global__ __launch_bounds__(256) void k_bucket(const int* __restrict__ ei, int* coarse_cur,
                                                u32* __restrict__ bpack, int* __restrict__ bsrc) {
    __shared__ u32 stageP[4096];
    __shared__ int stageS[4096];
    __shared__ int bcnt[256], bscan[256], boff[256], gbase[256];
    int t = threadIdx.x;
    int e0 = blockIdx.x * 4096;
    bcnt[t] = 0;
    __syncthreads();
    int dreg[16], sreg[16];
    for (int it = 0; it < 16; it++) {
        int e = e0 + it * 256 + t;
        int dd = ei[N_EDGES + e];
        dreg[it] = dd;
        sreg[it] = ei[e];
        atomicAdd(&bcnt[dd >> 8], 1);
    }
    __syncthreads();
    int v = bcnt[t];
    bscan[t] = v;
    __syncthreads();
    for (int off = 1; off < 256; off <<= 1) {
        int u = (t >= off) ? bscan[t - off] : 0;
        __syncthreads();
        bscan[t] += u;
        __syncthreads();
    }
    boff[t] = bscan[t] - v;
    gbase[t] = v ? atomicAdd(&coarse_cur[t], v) : 0;
    __syncthreads();
    for (int it = 0; it < 16; it++) {
        int e = e0 + it * 256 + t;
        int b = dreg[it] >> 8;
        int pos = atomicAdd(&boff[b], 1);
        stageP[pos] = ((u32)e << 12) | (u32)(dreg[it] & 255);
        stageS[pos] = sreg[it];
    }
    __syncthreads();
    for (int idx = t; idx < 4096; idx += 256) {
        int lo = 0, hi = 255;
        while (lo < hi) { int mid = (lo + hi) >> 1; if (bscan[mid] > idx) hi = mid; else lo = mid + 1; }
        int b = lo;
        int g = gbase[b] + (idx - (bscan[b] - bcnt[b]));
        bpack[g] = stageP[idx];
        bsrc[g] = stageS[idx];
    }
}

// ---------- local sort within bucket, fused with payload (a1es/a2es at scatter time) ----------
__global__ __launch_bounds__(256) void k_sortp(const u32* __restrict__ bpack, const int* __restrict__ bsrc,
                                               const int* __restrict__ row_ptr, const float* __restrict__ ea,
                                               const float* __restrict__ M1, const float* __restrict__ M2,
                                               int* __restrict__ ssrc, float* __restrict__ a1es,
                                               float* __restrict__ a2es) {
    __shared__ int cur[256];
    int t = threadIdx.x, b = blockIdx.x;
    int nbase = b * 256;
    cur[t] = row_ptr[nbase + t];
    __syncthreads();
    float m1[20], m2[5];
    #pragma unroll
    for (int j = 0; j < 20; j++) m1[j] = M1[j];
    #pragma unroll
    for (int j = 0; j < 5; j++) m2[j] = M2[j];
    int beg = row_ptr[nbase];
    int end = row_ptr[nbase + 256];
    for (int i = beg + t; i < end; i += 256) {
        u32 wd = bpack[i];
        int src = bsrc[i];
        int d8 = wd & 255;
        int e = (int)(wd >> 12);
        int pos = atomicAdd(&cur[d8], 1);
        ssrc[pos] = src;
        const float* ep = ea + (size_t)e * 5;
        float v0 = ep[0], v1 = ep[1], v2 = ep[2], v3 = ep[3], v4 = ep[4];
        float4 o;
        o.x = v0*m1[0]  + v1*m1[4]  + v2*m1[8]  + v3*m1[12] + v4*m1[16];
        o.y = v0*m1[1]  + v1*m1[5]  + v2*m1[9]  + v3*m1[13] + v4*m1[17];
        o.z = v0*m1[2]  + v1*m1[6]  + v2*m1[10] + v3*m1[14] + v4*m1[18];
        o.w = v0*m1[3]  + v1*m1[7]  + v2*m1[11] + v3*m1[15] + v4*m1[19];
        *(float4*)(a1es + (size_t)pos * 4) = o;
        a2es[pos] = v0*m2[0] + v1*m2[1] + v2*m2[2] + v3*m2[3] + v4*m2[4];
    }
}

// ---------- featb[n][0..63] = relu(roi @ roiW + b) via MFMA; [64..76]=x(bf16); [77..127]=0 ----------
__global__ __launch_bounds__(256) void k_vis(const float* __restrict__ roi, const u16* __restrict__ Wt,
                                             const float* __restrict__ bias, const float* __restrict__ x,
                                             u16* __restrict__ featb) {
    __shared__ u16 At[64][264];
    int t = threadIdx.x;
    int w = t >> 6, l = t & 63, lo = l & 15, hi = l >> 4;
    int n0 = blockIdx.x * 64;
    int r = t >> 2, sub = t & 3;
    const float* rp = roi + (size_t)(n0 + r) * 256 + sub * 4;
    #pragma unroll
    for (int q = 0; q < 16; q++) {
        float4 v = *(const float4*)(rp + q * 16);
        uint2 p;
        p.x = pk2(v.x, v.y);
        p.y = pk2(v.z, v.w);
        *(uint2*)&At[r][q * 16 + sub * 4] = p;
    }
    {   // x part + zero pad
        u16* fb = featb + (size_t)(n0 + r) * 128;
        if (sub == 0) {
            const float* xp = x + (size_t)(n0 + r) * 13;
            #pragma unroll
            for (int j = 0; j < 13; j++) fb[64 + j] = f2bf(xp[j]);
        } else {
            int j0 = 77 + (sub - 1) * 17;
            #pragma unroll
            for (int j = 0; j < 17; j++) fb[j0 + j] = 0;
        }
    }
    float bb[4][4];
    #pragma unroll
    for (int cb = 0; cb < 4; cb++)
        #pragma unroll
        for (int rg = 0; rg < 4; rg++) bb[cb][rg] = bias[cb * 16 + hi * 4 + rg];
    __syncthreads();
    f32x4 acc[4];
    #pragma unroll
    for (int cb = 0; cb < 4; cb++) acc[cb] = (f32x4){0.f, 0.f, 0.f, 0.f};
    #pragma unroll
    for (int ks = 0; ks < 8; ks++) {
        bf16x8 af = *(const bf16x8*)(&At[w * 16 + lo][ks * 32 + hi * 8]);
        #pragma unroll
        for (int cb = 0; cb < 4; cb++) {
            bf16x8 wf = *(const bf16x8*)(Wt + (size_t)(cb * 16 + lo) * 256 + ks * 32 + hi * 8);
            acc[cb] = __builtin_amdgcn_mfma_f32_16x16x32_bf16(wf, af, acc[cb], 0, 0, 0);
        }
    }
    int nrow = n0 + w * 16 + lo;
    #pragma unroll
    for (int cb = 0; cb < 4; cb++) {
        uint2 p;
        p.x = pk2(fmaxf(acc[cb][0] + bb[cb][0], 0.f), fmaxf(acc[cb][1] + bb[cb][1], 0.f));
        p.y = pk2(fmaxf(acc[cb][2] + bb[cb][2], 0.f), fmaxf(acc[cb][3] + bb[cb][3], 0.f));
        *(uint2*)(featb + (size_t)nrow * 128 + cb * 16 + hi * 4) = p;
    }
}

// ---------- a1s/a1d[n][h] = featb[n] . v1{s,d}[h] ----------
__global__ __launch_bounds__(256) void k_a1(const u16* __restrict__ featb, const float* __restrict__ v1s,
                                            const float* __restrict__ v1d,
                                            float* __restrict__ a1s, float* __restrict__ a1d) {
    __shared__ float vs[512], vd[512];
    int t = threadIdx.x;
    for (int idx = t; idx < 512; idx += 256) { vs[idx] = v1s[idx]; vd[idx] = v1d[idx]; }
    __syncthreads();
    int n = blockIdx.x * 32 + (t >> 3), l8 = t & 7;
    const uint4* fp = (const uint4*)(featb + (size_t)n * 128 + l8 * 16);
    uint4 u0 = fp[0], u1 = fp[1];
    float f[16];
    f[0]=lo16(u0.x); f[1]=hi16(u0.x); f[2]=lo16(u0.y); f[3]=hi16(u0.y);
    f[4]=lo16(u0.z); f[5]=hi16(u0.z); f[6]=lo16(u0.w); f[7]=hi16(u0.w);
    f[8]=lo16(u1.x); f[9]=hi16(u1.x); f[10]=lo16(u1.y); f[11]=hi16(u1.y);
    f[12]=lo16(u1.z); f[13]=hi16(u1.z); f[14]=lo16(u1.w); f[15]=hi16(u1.w);
    float as4[4], ad4[4];
    #pragma unroll
    for (int h = 0; h < 4; h++) {
        float s = 0.f, d = 0.f;
        #pragma unroll
        for (int q = 0; q < 4; q++) {
            float4 v4 = *(const float4*)&vs[h * 128 + l8 * 16 + q * 4];
            float4 w4 = *(const float4*)&vd[h * 128 + l8 * 16 + q * 4];
            s += f[q*4+0]*v4.x + f[q*4+1]*v4.y + f[q*4+2]*v4.z + f[q*4+3]*v4.w;
            d += f[q*4+0]*w4.x + f[q*4+1]*w4.y + f[q*4+2]*w4.z + f[q*4+3]*w4.w;
        }
        as4[h] = s; ad4[h] = d;
    }
    #pragma unroll
    for (int h = 0; h < 4; h++) {
        for (int o = 1; o < 8; o <<= 1) {
            as4[h] += __shfl_xor(as4[h], o, 64);
            ad4[h] += __shfl_xor(ad4[h], o, 64);
        }
    }
    if (l8 == 0) {
        *(float4*)(a1s + (size_t)n * 4) = make_float4(as4[0], as4[1], as4[2], as4[3]);
        *(float4*)(a1d + (size_t)n * 4) = make_float4(ad4[0], ad4[1], ad4[2], ad4[3]);
    }
}

// ---------- GAT1 fused softmax + FEAT-space gather: one wave per node, no cross-wave barrier ----------
// phase1: logits -> per-wave LDS (wl), ssrc cached in LDS (sl), online (m,s), rewrite wl to alpha
// phase2: software-pipelined G[n][h][128] = sum_e alpha[e][h] * featb[src_e]
__global__ __launch_bounds__(256) void k_sg1g(const int* __restrict__ row_ptr, const int* __restrict__ ssrc,
                                              const float* __restrict__ a1s, const float* __restrict__ a1d,
                                              const float* __restrict__ a1es, const u16* __restrict__ featb,
                                              u16* __restrict__ G) {
    __shared__ float wl[4][1024];   // per-wave: [edge<256][head<4]
    __shared__ int   sl[4][256];    // per-wave ssrc cache
    int t = threadIdx.x;
    int wv = t >> 6, L = t & 63;
    int n = blockIdx.x * 4 + wv;
    int beg = row_ptr[n], deg = row_ptr[n + 1] - beg;
    int lim = (deg < 256) ? deg : 256;
    {   // ---- phase 1 ----
        int h = L >> 4, j = L & 15;
        float adn = a1d[n * 4 + h];
        float m = -3.0e38f, s = 0.f;
        for (int i = j; i < deg; i += 16) {
            int pos = beg + i;
            int sv = ssrc[pos];
            if (h == 0 && i < 256) sl[wv][i] = sv;
            float l = a1s[sv * 4 + h] + adn + a1es[(size_t)pos * 4 + h];
            l = (l > 0.f) ? l : 0.2f * l;
            if (i < 256) wl[wv][i * 4 + h] = l;
            if (l > m) { s = s * __expf(m - l) + 1.f; m = l; }
            else       { s += __expf(l - m); }
        }
        for (int o = 1; o < 16; o <<= 1) {
            float mo = __shfl_xor(m, o, 64), so = __shfl_xor(s, o, 64);
            float M = fmaxf(m, mo);
            s = s * __expf(m - M) + so * __expf(mo - M);
            m = M;
        }
        float inv = 1.f / (s + 1e-16f);
        for (int i = j; i < lim; i += 16)
            wl[wv][i * 4 + h] = __expf(wl[wv][i * 4 + h] - m) * inv;
    }
    // in-wave LDS handoff: keep program order, drain LDS ops (no __syncthreads: waves independent)
    asm volatile("" ::: "memory");
    __builtin_amdgcn_s_waitcnt(0);
    // ---- phase 2: 4 edges/iter x 16 channel-group lanes, 1-deep pipelined ----
    int es = L >> 4;        // edge sub-slot 0..3
    int cg = L & 15;        // channel group: ch = cg*8 .. +7
    float acc[4][8];
    #pragma unroll
    for (int h = 0; h < 4; h++)
        #pragma unroll
        for (int j2 = 0; j2 < 8; j2++) acc[h][j2] = 0.f;
    int ii0 = es;
    bool v0 = ii0 < deg;
    int s0 = v0 ? sl[wv][ii0] : 0;
    float4 al0 = v0 ? *(const float4*)&wl[wv][ii0 * 4] : make_float4(0.f, 0.f, 0.f, 0.f);
    uint4 u0 = *((const uint4*)(featb + (size_t)s0 * 128) + cg);
    for (int i = 0; i < deg; i += 4) {
        int iin = i + 4 + es;
        bool vn = iin < deg;
        int sn = vn ? sl[wv][iin] : 0;
        float4 aln = vn ? *(const float4*)&wl[wv][iin * 4] : make_float4(0.f, 0.f, 0.f, 0.f);
        uint4 un = *((const uint4*)(featb + (size_t)sn * 128) + cg);
        float f0 = lo16(u0.x), f1 = hi16(u0.x), f2 = lo16(u0.y), f3 = hi16(u0.y);
        float f4 = lo16(u0.z), f5 = hi16(u0.z), f6 = lo16(u0.w), f7 = hi16(u0.w);
        #pragma unroll
        for (int h = 0; h < 4; h++) {
            float a = (&al0.x)[h];
            acc[h][0] += a * f0; acc[h][1] += a * f1;
            acc[h][2] += a * f2; acc[h][3] += a * f3;
            acc[h][4] += a * f4; acc[h][5] += a * f5;
            acc[h][6] += a * f6; acc[h][7] += a * f7;
        }
        u0 = un; al0 = aln;
    }
    #pragma unroll
    for (int h = 0; h < 4; h++)
        #pragma unroll
        for (int j2 = 0; j2 < 8; j2++) {
            acc[h][j2] += __shfl_xor(acc[h][j2], 16, 64);
            acc[h][j2] += __shfl_xor(acc[h][j2], 32, 64);
        }
    if (es == 0) {
        #pragma unroll
        for (int h = 0; h < 4; h++) {
            uint4 p;
            p.x = pk2(acc[h][0], acc[h][1]);
            p.y = pk2(acc[h][2], acc[h][3]);
            p.z = pk2(acc[h][4], acc[h][5]);
            p.w = pk2(acc[h][6], acc[h][7]);
            *((uint4*)(G + ((size_t)n * 4 + h) * 128) + cg) = p;
        }
    }
}

// ---------- fused: out1 = relu(G @ g1Wt + b1) [LDS only] ; h2 = out1 @ g2Wt ; a2s/a2d ----------
// wave w owns 16 nodes. stage1: per head, MFMA G x W1 -> out1 tile in swizzled LDS (bf16).
// stage2: MFMA W2 x out1 -> h2b + fused a2s/a2d. out1 never touches global memory.
__global__ __launch_bounds__(256) void k_goh(const u16* __restrict__ G, const u16* __restrict__ Wt1,
                                             const float* __restrict__ b1, const u16* __restrict__ Wt2,
                                             const float* __restrict__ as_, const float* __restrict__ ad_,
                                             u16* __restrict__ h2b, float* __restrict__ a2s,
                                             float* __restrict__ a2d) {
    __shared__ u16 T[4][4096];      // per-wave 16 nodes x 256 ch (bf16), XOR-swizzled
    int t = threadIdx.x;
    int w = t >> 6, l = t & 63, lo = l & 15, hi = l >> 4;
    int nrow = blockIdx.x * 64 + w * 16 + lo;
    char* Tw = (char*)&T[w][0];
    // ---- stage 1: out1 = relu(G @ W1 + b1), per head ----
    #pragma unroll
    for (int h = 0; h < 4; h++) {
        const u16* gp = G + ((size_t)nrow * 4 + h) * 128 + hi * 8;
        bf16x8 af0 = *(const bf16x8*)(gp);
        bf16x8 af1 = *(const bf16x8*)(gp + 32);
        bf16x8 af2 = *(const bf16x8*)(gp + 64);
        bf16x8 af3 = *(const bf16x8*)(gp + 96);
        f32x4 acc[4];
        #pragma unroll
        for (int cb = 0; cb < 4; cb++) acc[cb] = (f32x4){0.f, 0.f, 0.f, 0.f};
        #pragma unroll
        for (int cb = 0; cb < 4; cb++) {
            const u16* wp = Wt1 + (size_t)(h * 64 + cb * 16 + lo) * 128 + hi * 8;
            acc[cb] = __builtin_amdgcn_mfma_f32_16x16x32_bf16(*(const bf16x8*)(wp),       af0, acc[cb], 0, 0, 0);
            acc[cb] = __builtin_amdgcn_mfma_f32_16x16x32_bf16(*(const bf16x8*)(wp + 32),  af1, acc[cb], 0, 0, 0);
            acc[cb] = __builtin_amdgcn_mfma_f32_16x16x32_bf16(*(const bf16x8*)(wp + 64),  af2, acc[cb], 0, 0, 0);
            acc[cb] = __builtin_amdgcn_mfma_f32_16x16x32_bf16(*(const bf16x8*)(wp + 96),  af3, acc[cb], 0, 0, 0);
        }
        #pragma unroll
        for (int cb = 0; cb < 4; cb++) {
            int ch0 = h * 64 + cb * 16 + hi * 4;
            float4 bb = *(const float4*)(b1 + ch0);
            uint2 p;
            p.x = pk2(fmaxf(acc[cb][0] + bb.x, 0.f), fmaxf(acc[cb][1] + bb.y, 0.f));
            p.y = pk2(fmaxf(acc[cb][2] + bb.z, 0.f), fmaxf(acc[cb][3] + bb.w, 0.f));
            u32 byte = (u32)(lo * 512 + ch0 * 2) ^ ((u32)(lo & 7) << 4);
            *(uint2*)(Tw + byte) = p;
        }
    }
    __syncthreads();
    // ---- stage 2: h2 = out1 @ W2, K=256 ----
    f32x4 acc2[4];
    #pragma unroll
    for (int cb = 0; cb < 4; cb++) acc2[cb] = (f32x4){0.f, 0.f, 0.f, 0.f};
    #pragma unroll
    for (int ks = 0; ks < 8; ks++) {
        u32 byte = (u32)(lo * 512 + (ks * 32 + hi * 8) * 2) ^ ((u32)(lo & 7) << 4);
        bf16x8 bf = *(const bf16x8*)(Tw + byte);
        #pragma unroll
        for (int cb = 0; cb < 4; cb++) {
            bf16x8 wf = *(const bf16x8*)(Wt2 + (size_t)(cb * 16 + lo) * 256 + ks * 32 + hi * 8);
            acc2[cb] = __builtin_amdgcn_mfma_f32_16x16x32_bf16(wf, bf, acc2[cb], 0, 0, 0);
        }
    }
    float ps = 0.f, pd = 0.f;
    #pragma unroll
    for (int cb = 0; cb < 4; cb++) {
        uint2 p;
        p.x = pk2(acc2[cb][0], acc2[cb][1]);
        p.y = pk2(acc2[cb][2], acc2[cb][3]);
        *(uint2*)(h2b + (size_t)nrow * 64 + cb * 16 + hi * 4) = p;
        #pragma unroll
        for (int rg = 0; rg < 4; rg++) {
            float a = acc2[cb][rg];
            ps += a * as_[cb * 16 + hi * 4 + rg];
            pd += a * ad_[cb * 16 + hi * 4 + rg];
        }
    }
    ps += __shfl_xor(ps, 16, 64); ps += __shfl_xor(ps, 32, 64);
    pd += __shfl_xor(pd, 16, 64); pd += __shfl_xor(pd, 32, 64);
    if (hi == 0) {
        a2s[nrow] = ps;
        a2d[nrow] = pd;
    }
}

// ---------- GAT2 fused softmax+gather: one wave per node ----------
__global__ __launch_bounds__(256) void k_sg2(const int* __restrict__ row_ptr, const int* __restrict__ ssrc,
                                             const float* __restrict__ a2s, const float* __restrict__ a2d,
                                             const float* __restrict__ a2es, const u16* __restrict__ h2b,
                                             const float* __restrict__ bias, float* __restrict__ hfin) {
    __shared__ float wl[4][256];
    int t = threadIdx.x;
    int wv = t >> 6, L = t & 63;
    int n = blockIdx.x * 4 + wv;
    int beg = row_ptr[n], deg = row_ptr[n + 1] - beg;
    int lim = (deg < 256) ? deg : 256;
    {   // ---- phase 1 ----
        float adn = a2d[n];
        float m = -3.0e38f, s = 0.f;
        for (int i = L; i < deg; i += 64) {
            int pos = beg + i;
            float l = a2s[ssrc[pos]] + adn + a2es[pos];
            l = (l > 0.f) ? l : 0.2f * l;
            if (i < 256) wl[wv][i] = l;
            if (l > m) { s = s * __expf(m - l) + 1.f; m = l; }
            else       { s += __expf(l - m); }
        }
        for (int o = 1; o < 64; o <<= 1) {
            float mo = __shfl_xor(m, o, 64), so = __shfl_xor(s, o, 64);
            float M = fmaxf(m, mo);
            s = s * __expf(m - M) + so * __expf(mo - M);
            m = M;
        }
        float inv = 1.f / (s + 1e-16f);
        for (int i = L; i < lim; i += 64)
            wl[wv][i] = __expf(wl[wv][i] - m) * inv;
    }
    __syncthreads();
    // ---- phase 2 ----
    int halfE = L >> 5;
    int L32 = L & 31;
    float a0 = 0.f, a1v = 0.f;
    int last = beg + deg - 1;
    const u32* h2u = (const u32*)h2b;
    for (int i = 0; i < deg; i += 8) {
        int iA = i + halfE, iB = i + 2 + halfE, iC = i + 4 + halfE, iD = i + 6 + halfE;
        bool vA = iA < deg, vB = iB < deg, vC = iC < deg, vD = iD < deg;
        int cA = vA ? beg + iA : last, cB = vB ? beg + iB : last;
        int cC = vC ? beg + iC : last, cD = vD ? beg + iD : last;
        int sA = ssrc[cA], sB = ssrc[cB], sC = ssrc[cC], sD = ssrc[cD];
        float wA = vA ? wl[wv][iA] : 0.f;
        float wB = vB ? wl[wv][iB] : 0.f;
        float wC = vC ? wl[wv][iC] : 0.f;
        float wD = vD ? wl[wv][iD] : 0.f;
        u32 uA = h2u[(size_t)sA * 32 + L32];
        u32 uB = h2u[(size_t)sB * 32 + L32];
        u32 uC = h2u[(size_t)sC * 32 + L32];
        u32 uD = h2u[(size_t)sD * 32 + L32];
        a0  += wA * lo16(uA) + wB * lo16(uB) + wC * lo16(uC) + wD * lo16(uD);
        a1v += wA * hi16(uA) + wB * hi16(uB) + wC * hi16(uC) + wD * hi16(uD);
    }
    a0  += __shfl_xor(a0, 32, 64);
    a1v += __shfl_xor(a1v, 32, 64);
    if (halfE == 0) {
        float2 o;
        o.x = a0  + bias[2 * L32];
        o.y = a1v + bias[2 * L32 + 1];
        *(float2*)(hfin + (size_t)n * 64 + 2 * L32) = o;
    }
}

// ---------- pooling + classifier ----------
__global__ __launch_bounds__(64) void k_pool(const int* __restrict__ bvec, const float* __restrict__ hf,
                                             const float* gateW, const float* gateb,
                                             const float* __restrict__ scene,
                                             const float* c1W, const float* c1b,
                                             const float* c2W, const float* c2b,
                                             float* __restrict__ outp) {
    int b = blockIdx.x, lane = threadIdx.x;
    __shared__ float gwl[64], se[64], comb[192], hid[64];
    gwl[lane] = gateW[lane];
    __syncthreads();
    int s0, s1;
    { int lo = 0, hi = N_NODES; while (lo < hi) { int mid = (lo + hi) >> 1; if (bvec[mid] < b) lo = mid + 1; else hi = mid; } s0 = lo; }
    { int lo = 0, hi = N_NODES; while (lo < hi) { int mid = (lo + hi) >> 1; if (bvec[mid] < b + 1) lo = mid + 1; else hi = mid; } s1 = lo; }
    float gb = gateb[0];
    float m = -3.0e38f, ssum = 0.f, acc = 0.f;
    for (int cs = s0; cs < s1; cs += 64) {
        int cnt = min(64, s1 - cs);
        float l = -3.0e38f;
        if (lane < cnt) {
            int n = cs + lane;
            float d = 0.f;
            for (int i = 0; i < 64; i++) d += hf[(size_t)n * 64 + i] * gwl[i];
            l = d + gb;
        }
        float cm = wmax(l);
        float newm = fmaxf(m, cm);
        float rsc = __expf(m - newm);
        float e = (lane < cnt) ? __expf(l - newm) : 0.f;
        float es = wsum(e);
        ssum = ssum * rsc + es;
        se[lane] = e;
        __syncthreads();
        float a2 = 0.f;
        for (int i = 0; i < cnt; i++) a2 += se[i] * hf[(size_t)(cs + i) * 64 + lane];
        acc = acc * rsc + a2;
        __syncthreads();
        m = newm;
    }
    float rel = acc / (ssum + 1e-16f);
    comb[lane] = scene[b * 128 + lane];
    comb[64 + lane] = scene[b * 128 + 64 + lane];
    comb[128 + lane] = rel;
    __syncthreads();
    float hj = 0.f;
    for (int k = 0; k < 192; k++) hj += comb[k] * c1W[k * 64 + lane];
    hj += c1b[lane];
    hid[lane] = fmaxf(hj, 0.f);
    __syncthreads();
    if (lane < 3) {
        float o = 0.f;
        for (int k = 0; k < 64; k++) o += hid[k] * c2W[k * 3 + lane];
        o += c2b[lane];
        outp[b * 3 + lane] = o;
    }
}

extern "C" void kernel_launch(void* const* d_in, const int* in_sizes, int n_in,
                              void* d_out, int out_size, void* d_ws, size_t ws_size,
                              hipStream_t stream) {
    (void)in_sizes; (void)n_in; (void)out_size; (void)ws_size;
    const float* gf     = (const float*)d_in[0];
    const float* x      = (const float*)d_in[1];
    const float* roi    = (const float*)d_in[2];
    const int*   ei     = (const int*)d_in[3];
    const float* ea     = (const float*)d_in[4];
    const int*   bvec   = (const int*)d_in[5];
    const float* roiW   = (const float*)d_in[6];
    const float* roib   = (const float*)d_in[7];
    const float* sceneW = (const float*)d_in[8];
    const float* sceneb = (const float*)d_in[9];
    const float* g1W    = (const float*)d_in[10];
    const float* g1as   = (const float*)d_in[11];
    const float* g1ad   = (const float*)d_in[12];
    const float* g1We   = (const float*)d_in[13];
    const float* g1ae   = (const float*)d_in[14];
    const float* g1b    = (const float*)d_in[15];
    const float* g2W    = (const float*)d_in[16];
    const float* g2as   = (const float*)d_in[17];
    const float* g2ad   = (const float*)d_in[18];
    const float* g2We   = (const float*)d_in[19];
    const float* g2ae   = (const float*)d_in[20];
    const float* g2b    = (const float*)d_in[21];
    const float* gateW  = (const float*)d_in[22];
    const float* gateb  = (const float*)d_in[23];
    const float* c1W    = (const float*)d_in[24];
    const float* c1b    = (const float*)d_in[25];
    const float* c2W    = (const float*)d_in[26];
    const float* c2b    = (const float*)d_in[27];

    char* w = (char*)d_ws;
    size_t o = 0;
    auto nxt = [&](size_t bytes) -> char* {
        char* p = w + o;
        o += (bytes + 255) & ~(size_t)255;
        return p;
    };
    float* scene  = (float*)nxt((size_t)NB * 128 * 4);
    float* M1     = (float*)nxt(80);
    float* M2     = (float*)nxt(32);
    u16* g1Wt     = (u16*)nxt((size_t)256 * 128 * 2);
    u16* roiWt    = (u16*)nxt((size_t)64 * 256 * 2);
    u16* g2Wt     = (u16*)nxt((size_t)64 * 256 * 2);
    float* v1s    = (float*)nxt(512 * 4);
    float* v1d    = (float*)nxt(512 * 4);
    int* cnt      = (int*)nxt((size_t)N_NODES * 4);
    int* pre      = (int*)nxt((size_t)N_NODES * 4);
    int* bsum     = (int*)nxt(64 * 4);
    int* row_ptr  = (int*)nxt((size_t)(N_NODES + 1) * 4);
    int* coarse   = (int*)nxt(256 * 4);
    u32* bpack    = (u32*)nxt((size_t)N_EDGES * 4);
    int* bsrc     = (int*)nxt((size_t)N_EDGES * 4);
    int* ssrc     = (int*)nxt((size_t)N_EDGES * 4);
    float* a1es   = (float*)nxt((size_t)N_EDGES * 16);
    float* a2es   = (float*)nxt((size_t)N_EDGES * 4);
    u16* featb    = (u16*)nxt((size_t)N_NODES * 128 * 2);
    u16* G        = (u16*)nxt((size_t)N_NODES * 4 * 128 * 2);
    u16* h2b      = (u16*)nxt((size_t)N_NODES * 64 * 2);
    float* hfin   = (float*)nxt((size_t)N_NODES * 64 * 4);
    float* a1s    = (float*)nxt((size_t)N_NODES * 16);
    float* a1d    = (float*)nxt((size_t)N_NODES * 16);
    float* a2s    = (float*)nxt((size_t)N_NODES * 4);
    float* a2d    = (float*)nxt((size_t)N_NODES * 4);

    hipMemsetAsync(cnt, 0, (size_t)N_NODES * 4, stream);
    k_wprep<<<130, 512, 0, stream>>>(g1W, roiW, g2W, g1as, g1ad, g1We, g1ae, g2We, g2ae,
                                     g1Wt, roiWt, g2Wt, v1s, v1d, M1, M2);
    k_scene<<<(NB * 128) / 256, 256, 0, stream>>>(gf, sceneW, sceneb, scene);
    k_hist<<<N_EDGES / 256, 256, 0, stream>>>(ei, cnt);
    k_scan_blk<<<64, 256, 0, stream>>>(cnt, pre, bsum);
    k_scan_top<<<1, 64, 0, stream>>>(bsum);
    k_scan_fix<<<N_NODES / 256, 256, 0, stream>>>(pre, bsum, row_ptr, coarse);
    k_bucket<<<256, 256, 0, stream>>>(ei, coarse, bpack, bsrc);
    k_sortp<<<256, 256, 0, stream>>>(bpack, bsrc, row_ptr, ea, M1, M2, ssrc, a1es, a2es);
    k_vis<<<N_NODES / 64, 256, 0, stream>>>(roi, roiWt, roib, x, featb);
    k_a1<<<N_NODES / 32, 256, 0, stream>>>(featb, v1s, v1d, a1s, a1d);
    k_sg1g<<<N_NODES / 4, 256, 0, stream>>>(row_ptr, ssrc, a1s, a1d, a1es, featb, G);
    k_goh<<<N_NODES / 64, 256, 0, stream>>>(G, g1Wt, g1b, g2Wt, g2as, g2ad, h2b, a2s, a2d);
    k_sg2<<<N_NODES / 4, 256, 0, stream>>>(row_ptr, ssrc, a2s, a2d, a2es, h2b, g2b, hfin);
    k_pool<<<NB, 64, 0, stream>>>(bvec, hfin, gateW, gateb, scene, c1W, c1b, c2W, c2b, (float*)d_out);
}

// Round 5
// 538.382 us; speedup vs baseline: 1.0232x; 1.0105x over previous
//
#include <hip/hip_runtime.h>

#define N_NODES 65536
#define N_EDGES 1048576
#define NB      512

typedef unsigned short u16;
typedef unsigned int   u32;
typedef unsigned long long u64;

typedef __attribute__((ext_vector_type(8))) short bf16x8;
typedef __attribute__((ext_vector_type(4))) float f32x4;

__device__ __forceinline__ float bf2f(u16 u) { return __uint_as_float(((u32)u) << 16); }
__device__ __forceinline__ float lo16(u32 u) { return __uint_as_float(u << 16); }
__device__ __forceinline__ float hi16(u32 u) { return __uint_as_float(u & 0xffff0000u); }
__device__ __forceinline__ u16 f2bf(float f) {
    u32 u = __float_as_uint(f);
    u32 r = (u + 0x7fffu + ((u >> 16) & 1u)) >> 16;
    return (u16)r;
}
__device__ __forceinline__ u32 pk2(float a, float b) {
    return (u32)f2bf(a) | ((u32)f2bf(b) << 16);
}
__device__ __forceinline__ float wsum(float v) {
    for (int o = 32; o; o >>= 1) v += __shfl_xor(v, o, 64);
    return v;
}
__device__ __forceinline__ float wmax(float v) {
    for (int o = 32; o; o >>= 1) v = fmaxf(v, __shfl_xor(v, o, 64));
    return v;
}

// ---------- mega prep: all weight transposes + M1/M2 in one launch ----------
// blocks 0..47   : g1Wt[c][k']  (256 x 96, k' = vis-first reorder, bf16)
// blocks 48..79  : roiWt[c][k]  (64 x 256 bf16)
// blocks 80..111 : g2Wt[c][k]   (64 x 256 bf16)
// block 112      : M1 (20), M2 (5)
__global__ __launch_bounds__(512) void k_wprep(const float* __restrict__ g1W, const float* __restrict__ roiW,
                                               const float* __restrict__ g2W,
                                               const float* __restrict__ g1We, const float* __restrict__ g1ae,
                                               const float* __restrict__ g2We, const float* __restrict__ g2ae,
                                               u16* __restrict__ g1Wt, u16* __restrict__ roiWt,
                                               u16* __restrict__ g2Wt, float* __restrict__ M1,
                                               float* __restrict__ M2) {
    int b = blockIdx.x, t = threadIdx.x;
    if (b < 48) {
        int idx = b * 512 + t;          // 0..24575 = 256*96
        int c = idx / 96, k = idx - 96 * c;
        float v = 0.f;
        if (k < 77) {
            int ko = (k < 64) ? (13 + k) : (k - 64);
            v = g1W[(size_t)ko * 256 + c];
        }
        g1Wt[idx] = f2bf(v);
    } else if (b < 80) {
        int idx = (b - 48) * 512 + t;   // 0..16383 = 64*256
        int c = idx >> 8, k = idx & 255;
        roiWt[idx] = f2bf(roiW[(size_t)k * 64 + c]);
    } else if (b < 112) {
        int idx = (b - 80) * 512 + t;
        int c = idx >> 8, k = idx & 255;
        g2Wt[idx] = f2bf(g2W[(size_t)k * 64 + c]);
    } else {
        if (t < 20) {
            int j = t >> 2, h = t & 3;
            float s = 0.f;
            for (int c = 0; c < 64; c++) s += g1We[j * 256 + h * 64 + c] * g1ae[h * 64 + c];
            M1[t] = s;
        } else if (t < 25) {
            int j = t - 20;
            float s = 0.f;
            for (int c = 0; c < 64; c++) s += g2We[j * 64 + c] * g2ae[c];
            M2[j] = s;
        }
    }
}

// ---------- scene ----------
__global__ __launch_bounds__(256) void k_scene(const float* __restrict__ gf, const float* __restrict__ W,
                                               const float* __restrict__ bias, float* __restrict__ scene) {
    int idx = blockIdx.x * 256 + threadIdx.x;
    int b = idx >> 7, j = idx & 127;
    float acc = 0.f;
    for (int k = 0; k < 512; k++) acc += gf[b * 512 + k] * W[k * 128 + j];
    scene[idx] = acc + bias[j];
}

// ---------- histogram ----------
__global__ __launch_bounds__(256) void k_hist(const int* ei, int* cnt) {
    int e = blockIdx.x * 256 + threadIdx.x;
    atomicAdd(&cnt[ei[N_EDGES + e]], 1);
}

// ---------- hierarchical exclusive scan ----------
__global__ __launch_bounds__(256) void k_scan_blk(const int* __restrict__ cnt, int* __restrict__ pre,
                                                  int* __restrict__ bsum) {
    __shared__ int sd[256];
    int t = threadIdx.x, b = blockIdx.x;
    int base = b * 1024 + t * 4;
    int4 c = *(const int4*)(cnt + base);
    int s = c.x + c.y + c.z + c.w;
    sd[t] = s;
    __syncthreads();
    for (int off = 1; off < 256; off <<= 1) {
        int v = (t >= off) ? sd[t - off] : 0;
        __syncthreads();
        sd[t] += v;
        __syncthreads();
    }
    int excl = sd[t] - s;
    int4 p;
    p.x = excl;
    p.y = excl + c.x;
    p.z = excl + c.x + c.y;
    p.w = excl + c.x + c.y + c.z;
    *(int4*)(pre + base) = p;
    if (t == 255) bsum[b] = sd[255];
}

__global__ __launch_bounds__(64) void k_scan_top(int* bsum) {
    int t = threadIdx.x;
    int v = bsum[t];
    int inc = v;
    for (int off = 1; off < 64; off <<= 1) {
        int u = __shfl_up(inc, off, 64);
        if (t >= off) inc += u;
    }
    bsum[t] = inc - v;
}

__global__ __launch_bounds__(256) void k_scan_fix(const int* __restrict__ pre, const int* __restrict__ bsum,
                                                  int* __restrict__ row_ptr, int* __restrict__ coarse_cur) {
    int i = blockIdx.x * 256 + threadIdx.x;
    int v = pre[i] + bsum[i >> 10];
    row_ptr[i] = v;
    if ((i & 255) == 0) coarse_cur[i >> 8] = v;
    if (i == 0) row_ptr[N_NODES] = N_EDGES;
}

// ---------- bucket pass (512 blocks x 2048 edges for 2 blocks/CU) ----------
__global__ __launch_bounds__(256) void k_bucket(const int* __restrict__ ei, int* coarse_cur,
                                                u32* __restrict__ bpack, int* __restrict__ bsrc) {
    __shared__ u32 stageP[2048];
    __shared__ int stageS[2048];
    __shared__ int bcnt[256], bscan[256], boff[256], gbase[256];
    int t = threadIdx.x;
    int e0 = blockIdx.x * 2048;
    bcnt[t] = 0;
    __syncthreads();
    int dreg[8], sreg[8];
    for (int it = 0; it < 8; it++) {
        int e = e0 + it * 256 + t;
        int dd = ei[N_EDGES + e];
        dreg[it] = dd;
        sreg[it] = ei[e];
        atomicAdd(&bcnt[dd >> 8], 1);
    }
    __syncthreads();
    int v = bcnt[t];
    bscan[t] = v;
    __syncthreads();
    for (int off = 1; off < 256; off <<= 1) {
        int u = (t >= off) ? bscan[t - off] : 0;
        __syncthreads();
        bscan[t] += u;
        __syncthreads();
    }
    boff[t] = bscan[t] - v;
    gbase[t] = v ? atomicAdd(&coarse_cur[t], v) : 0;
    __syncthreads();
    for (int it = 0; it < 8; it++) {
        int e = e0 + it * 256 + t;
        int b = dreg[it] >> 8;
        int pos = atomicAdd(&boff[b], 1);
        stageP[pos] = ((u32)e << 12) | (u32)(dreg[it] & 255);
        stageS[pos] = sreg[it];
    }
    __syncthreads();
    for (int idx = t; idx < 2048; idx += 256) {
        int lo = 0, hi = 255;
        while (lo < hi) { int mid = (lo + hi) >> 1; if (bscan[mid] > idx) hi = mid; else lo = mid + 1; }
        int b = lo;
        int g = gbase[b] + (idx - (bscan[b] - bcnt[b]));
        bpack[g] = stageP[idx];
        bsrc[g] = stageS[idx];
    }
}

// ---------- local sort within bucket, fused with payload (a1es/a2es at scatter time) ----------
__global__ __launch_bounds__(256) void k_sortp(const u32* __restrict__ bpack, const int* __restrict__ bsrc,
                                               const int* __restrict__ row_ptr, const float* __restrict__ ea,
                                               const float* __restrict__ M1, const float* __restrict__ M2,
                                               int* __restrict__ ssrc, float* __restrict__ a1es,
                                               float* __restrict__ a2es) {
    __shared__ int cur[256];
    int t = threadIdx.x, b = blockIdx.x;
    int nbase = b * 256;
    cur[t] = row_ptr[nbase + t];
    __syncthreads();
    float m1[20], m2[5];
    #pragma unroll
    for (int j = 0; j < 20; j++) m1[j] = M1[j];
    #pragma unroll
    for (int j = 0; j < 5; j++) m2[j] = M2[j];
    int beg = row_ptr[nbase];
    int end = row_ptr[nbase + 256];
    for (int i = beg + t; i < end; i += 256) {
        u32 wd = bpack[i];
        int src = bsrc[i];
        int d8 = wd & 255;
        int e = (int)(wd >> 12);
        int pos = atomicAdd(&cur[d8], 1);
        ssrc[pos] = src;
        const float* ep = ea + (size_t)e * 5;
        float v0 = ep[0], v1 = ep[1], v2 = ep[2], v3 = ep[3], v4 = ep[4];
        float4 o;
        o.x = v0*m1[0]  + v1*m1[4]  + v2*m1[8]  + v3*m1[12] + v4*m1[16];
        o.y = v0*m1[1]  + v1*m1[5]  + v2*m1[9]  + v3*m1[13] + v4*m1[17];
        o.z = v0*m1[2]  + v1*m1[6]  + v2*m1[10] + v3*m1[14] + v4*m1[18];
        o.w = v0*m1[3]  + v1*m1[7]  + v2*m1[11] + v3*m1[15] + v4*m1[19];
        *(float4*)(a1es + (size_t)pos * 4) = o;
        a2es[pos] = v0*m2[0] + v1*m2[1] + v2*m2[2] + v3*m2[3] + v4*m2[4];
    }
}

// ---------- vis = relu(roi @ roiW + b) via MFMA, bf16 out [n][64] ----------
__global__ __launch_bounds__(256) void k_vis(const float* __restrict__ roi, const u16* __restrict__ Wt,
                                             const float* __restrict__ bias, u16* __restrict__ out) {
    __shared__ u16 At[64][264];
    int t = threadIdx.x;
    int w = t >> 6, l = t & 63, lo = l & 15, hi = l >> 4;
    int n0 = blockIdx.x * 64;
    int r = t >> 2, sub = t & 3;
    const float* rp = roi + (size_t)(n0 + r) * 256 + sub * 4;
    #pragma unroll
    for (int q = 0; q < 16; q++) {
        float4 v = *(const float4*)(rp + q * 16);
        uint2 p;
        p.x = pk2(v.x, v.y);
        p.y = pk2(v.z, v.w);
        *(uint2*)&At[r][q * 16 + sub * 4] = p;
    }
    float bb[4][4];
    #pragma unroll
    for (int cb = 0; cb < 4; cb++)
        #pragma unroll
        for (int rg = 0; rg < 4; rg++) bb[cb][rg] = bias[cb * 16 + hi * 4 + rg];
    __syncthreads();
    f32x4 acc[4];
    #pragma unroll
    for (int cb = 0; cb < 4; cb++) acc[cb] = (f32x4){0.f, 0.f, 0.f, 0.f};
    #pragma unroll
    for (int ks = 0; ks < 8; ks++) {
        bf16x8 af = *(const bf16x8*)(&At[w * 16 + lo][ks * 32 + hi * 8]);
        #pragma unroll
        for (int cb = 0; cb < 4; cb++) {
            bf16x8 wf = *(const bf16x8*)(Wt + (size_t)(cb * 16 + lo) * 256 + ks * 32 + hi * 8);
            acc[cb] = __builtin_amdgcn_mfma_f32_16x16x32_bf16(wf, af, acc[cb], 0, 0, 0);
        }
    }
    int nrow = n0 + w * 16 + lo;
    #pragma unroll
    for (int cb = 0; cb < 4; cb++) {
        uint2 p;
        p.x = pk2(fmaxf(acc[cb][0] + bb[cb][0], 0.f), fmaxf(acc[cb][1] + bb[cb][1], 0.f));
        p.y = pk2(fmaxf(acc[cb][2] + bb[cb][2], 0.f), fmaxf(acc[cb][3] + bb[cb][3], 0.f));
        *(uint2*)(out + (size_t)nrow * 64 + cb * 16 + hi * 4) = p;
    }
}

// ---------- h1 = [vis | x] @ g1Wt via MFMA, fused a1s/a1d ----------
__global__ __launch_bounds__(256) void k_h1(const float* __restrict__ x, const u16* __restrict__ vis,
                                            const u16* __restrict__ Wt,
                                            const float* __restrict__ as_, const float* __restrict__ ad_,
                                            u16* __restrict__ h1, float* __restrict__ a1s,
                                            float* __restrict__ a1d) {
    __shared__ u16 At[64][104];
    int t = threadIdx.x;
    int w = t >> 6, l = t & 63, lo = l & 15, hi = l >> 4;
    int n0 = blockIdx.x * 64;
    int r = t >> 2, sub = t & 3;
    {
        const uint4* vp = (const uint4*)(vis + (size_t)(n0 + r) * 64 + sub * 16);
        uint4 v0 = vp[0], v1 = vp[1];
        *(uint4*)&At[r][sub * 16] = v0;
        *(uint4*)&At[r][sub * 16 + 8] = v1;
        if (sub == 0) {
            const float* xp = x + (size_t)(n0 + r) * 13;
            #pragma unroll
            for (int j = 0; j < 13; j++) At[r][64 + j] = f2bf(xp[j]);
        } else if (sub == 1) {
            #pragma unroll
            for (int j = 77; j < 96; j++) At[r][j] = 0;
        }
    }
    bf16x8 wf[4][3];
    float asv[4][4], adv[4][4];
    #pragma unroll
    for (int cb = 0; cb < 4; cb++) {
        #pragma unroll
        for (int ks = 0; ks < 3; ks++)
            wf[cb][ks] = *(const bf16x8*)(Wt + (size_t)(w * 64 + cb * 16 + lo) * 96 + ks * 32 + hi * 8);
        #pragma unroll
        for (int rg = 0; rg < 4; rg++) {
            asv[cb][rg] = as_[w * 64 + cb * 16 + hi * 4 + rg];
            adv[cb][rg] = ad_[w * 64 + cb * 16 + hi * 4 + rg];
        }
    }
    __syncthreads();
    #pragma unroll
    for (int nb = 0; nb < 4; nb++) {
        f32x4 acc[4];
        #pragma unroll
        for (int cb = 0; cb < 4; cb++) acc[cb] = (f32x4){0.f, 0.f, 0.f, 0.f};
        #pragma unroll
        for (int ks = 0; ks < 3; ks++) {
            bf16x8 af = *(const bf16x8*)(&At[nb * 16 + lo][ks * 32 + hi * 8]);
            #pragma unroll
            for (int cb = 0; cb < 4; cb++)
                acc[cb] = __builtin_amdgcn_mfma_f32_16x16x32_bf16(wf[cb][ks], af, acc[cb], 0, 0, 0);
        }
        int nrow = n0 + nb * 16 + lo;
        float ps = 0.f, pd = 0.f;
        #pragma unroll
        for (int cb = 0; cb < 4; cb++) {
            uint2 p;
            p.x = pk2(acc[cb][0], acc[cb][1]);
            p.y = pk2(acc[cb][2], acc[cb][3]);
            *(uint2*)(h1 + (size_t)nrow * 256 + w * 64 + cb * 16 + hi * 4) = p;
            ps += acc[cb][0] * asv[cb][0] + acc[cb][1] * asv[cb][1]
                + acc[cb][2] * asv[cb][2] + acc[cb][3] * asv[cb][3];
            pd += acc[cb][0] * adv[cb][0] + acc[cb][1] * adv[cb][1]
                + acc[cb][2] * adv[cb][2] + acc[cb][3] * adv[cb][3];
        }
        ps += __shfl_xor(ps, 16, 64); ps += __shfl_xor(ps, 32, 64);
        pd += __shfl_xor(pd, 16, 64); pd += __shfl_xor(pd, 32, 64);
        if (hi == 0) {
            a1s[nrow * 4 + w] = ps;
            a1d[nrow * 4 + w] = pd;
        }
    }
}

// ---------- GAT1 fused softmax + gather (h1-space), ssrc LDS cache, pipelined ----------
__global__ __launch_bounds__(256) void k_sg1(const int* __restrict__ row_ptr, const int* __restrict__ ssrc,
                                             const float* __restrict__ a1s, const float* __restrict__ a1d,
                                             const float* __restrict__ a1es, const u16* __restrict__ h1,
                                             const float* __restrict__ bias, u16* __restrict__ out1) {
    __shared__ float wl[4][1024];   // per-wave: [edge<256][head<4]
    __shared__ int   sl[4][256];    // per-wave ssrc cache
    int t = threadIdx.x;
    int wv = t >> 6, L = t & 63;
    int n = blockIdx.x * 4 + wv;
    int beg = row_ptr[n], deg = row_ptr[n + 1] - beg;
    int lim = (deg < 256) ? deg : 256;
    {   // ---- phase 1 ----
        int h = L >> 4, j = L & 15;
        float adn = a1d[n * 4 + h];
        float m = -3.0e38f, s = 0.f;
        for (int i = j; i < deg; i += 16) {
            int pos = beg + i;
            int sv = ssrc[pos];
            if (h == 0 && i < 256) sl[wv][i] = sv;
            float l = a1s[sv * 4 + h] + adn + a1es[(size_t)pos * 4 + h];
            l = (l > 0.f) ? l : 0.2f * l;
            if (i < 256) wl[wv][i * 4 + h] = l;
            if (l > m) { s = s * __expf(m - l) + 1.f; m = l; }
            else       { s += __expf(l - m); }
        }
        for (int o = 1; o < 16; o <<= 1) {
            float mo = __shfl_xor(m, o, 64), so = __shfl_xor(s, o, 64);
            float M = fmaxf(m, mo);
            s = s * __expf(m - M) + so * __expf(mo - M);
            m = M;
        }
        float inv = 1.f / (s + 1e-16f);
        for (int i = j; i < lim; i += 16)
            wl[wv][i * 4 + h] = __expf(wl[wv][i * 4 + h] - m) * inv;
    }
    // in-wave LDS handoff (waves independent; drain this wave's LDS ops)
    asm volatile("" ::: "memory");
    __builtin_amdgcn_s_waitcnt(0);
    // ---- phase 2: 8 edges/iter (2 half-lanes x 4 slots), 1-deep pipelined ----
    int halfE = L >> 5;
    int L32 = L & 31;
    int hd = L32 >> 3;
    float acc[8];
    #pragma unroll
    for (int j = 0; j < 8; j++) acc[j] = 0.f;
    uint4 U[4];
    float W[4];
    #pragma unroll
    for (int k = 0; k < 4; k++) {
        int ii = 2 * k + halfE;
        bool v = ii < deg;
        int s = v ? sl[wv][ii] : 0;
        W[k] = v ? wl[wv][ii * 4 + hd] : 0.f;
        U[k] = *((const uint4*)(h1 + (size_t)s * 256) + L32);
    }
    for (int i = 0; i < deg; i += 8) {
        uint4 C0 = U[0], C1 = U[1], C2 = U[2], C3 = U[3];
        float W0 = W[0], W1 = W[1], W2 = W[2], W3 = W[3];
        int ib = i + 8;
        #pragma unroll
        for (int k = 0; k < 4; k++) {
            int ii = ib + 2 * k + halfE;
            bool v = ii < deg;
            int s = v ? sl[wv][ii] : 0;
            W[k] = v ? wl[wv][ii * 4 + hd] : 0.f;
            U[k] = *((const uint4*)(h1 + (size_t)s * 256) + L32);
        }
        acc[0] += W0 * lo16(C0.x) + W1 * lo16(C1.x) + W2 * lo16(C2.x) + W3 * lo16(C3.x);
        acc[1] += W0 * hi16(C0.x) + W1 * hi16(C1.x) + W2 * hi16(C2.x) + W3 * hi16(C3.x);
        acc[2] += W0 * lo16(C0.y) + W1 * lo16(C1.y) + W2 * lo16(C2.y) + W3 * lo16(C3.y);
        acc[3] += W0 * hi16(C0.y) + W1 * hi16(C1.y) + W2 * hi16(C2.y) + W3 * hi16(C3.y);
        acc[4] += W0 * lo16(C0.z) + W1 * lo16(C1.z) + W2 * lo16(C2.z) + W3 * lo16(C3.z);
        acc[5] += W0 * hi16(C0.z) + W1 * hi16(C1.z) + W2 * hi16(C2.z) + W3 * hi16(C3.z);
        acc[6] += W0 * lo16(C0.w) + W1 * lo16(C1.w) + W2 * lo16(C2.w) + W3 * lo16(C3.w);
        acc[7] += W0 * hi16(C0.w) + W1 * hi16(C1.w) + W2 * hi16(C2.w) + W3 * hi16(C3.w);
    }
    #pragma unroll
    for (int j = 0; j < 8; j++) acc[j] += __shfl_xor(acc[j], 32, 64);
    if (halfE == 0) {
        float4 b0 = *(const float4*)(bias + 8 * L32);
        float4 b1 = *(const float4*)(bias + 8 * L32 + 4);
        uint4 pk;
        pk.x = (u32)f2bf(fmaxf(acc[0] + b0.x, 0.f)) | ((u32)f2bf(fmaxf(acc[1] + b0.y, 0.f)) << 16);
        pk.y = (u32)f2bf(fmaxf(acc[2] + b0.z, 0.f)) | ((u32)f2bf(fmaxf(acc[3] + b0.w, 0.f)) << 16);
        pk.z = (u32)f2bf(fmaxf(acc[4] + b1.x, 0.f)) | ((u32)f2bf(fmaxf(acc[5] + b1.y, 0.f)) << 16);
        pk.w = (u32)f2bf(fmaxf(acc[6] + b1.z, 0.f)) | ((u32)f2bf(fmaxf(acc[7] + b1.w, 0.f)) << 16);
        *((uint4*)(out1 + (size_t)n * 256) + L32) = pk;
    }
}

// ---------- h2 = out1(bf16) @ g2Wt via MFMA, no LDS, fused a2s/a2d ----------
__global__ __launch_bounds__(256) void k_h2(const u16* __restrict__ A, const u16* __restrict__ Wt,
                                            const float* __restrict__ as_, const float* __restrict__ ad_,
                                            u16* __restrict__ out, float* __restrict__ a2s,
                                            float* __restrict__ a2d) {
    int t = threadIdx.x;
    int w = t >> 6, l = t & 63, lo = l & 15, hi = l >> 4;
    int nrow = blockIdx.x * 64 + w * 16 + lo;
    f32x4 acc[4];
    #pragma unroll
    for (int cb = 0; cb < 4; cb++) acc[cb] = (f32x4){0.f, 0.f, 0.f, 0.f};
    const u16* ap = A + (size_t)nrow * 256 + hi * 8;
    #pragma unroll
    for (int ks = 0; ks < 8; ks++) {
        bf16x8 af = *(const bf16x8*)(ap + ks * 32);
        #pragma unroll
        for (int cb = 0; cb < 4; cb++) {
            bf16x8 wf = *(const bf16x8*)(Wt + (size_t)(cb * 16 + lo) * 256 + ks * 32 + hi * 8);
            acc[cb] = __builtin_amdgcn_mfma_f32_16x16x32_bf16(wf, af, acc[cb], 0, 0, 0);
        }
    }
    float ps = 0.f, pd = 0.f;
    #pragma unroll
    for (int cb = 0; cb < 4; cb++) {
        uint2 p;
        p.x = pk2(acc[cb][0], acc[cb][1]);
        p.y = pk2(acc[cb][2], acc[cb][3]);
        *(uint2*)(out + (size_t)nrow * 64 + cb * 16 + hi * 4) = p;
        #pragma unroll
        for (int rg = 0; rg < 4; rg++) {
            float a = acc[cb][rg];
            ps += a * as_[cb * 16 + hi * 4 + rg];
            pd += a * ad_[cb * 16 + hi * 4 + rg];
        }
    }
    ps += __shfl_xor(ps, 16, 64); ps += __shfl_xor(ps, 32, 64);
    pd += __shfl_xor(pd, 16, 64); pd += __shfl_xor(pd, 32, 64);
    if (hi == 0) {
        a2s[nrow] = ps;
        a2d[nrow] = pd;
    }
}

// ---------- GAT2 fused softmax+gather, ssrc LDS cache, pipelined ----------
__global__ __launch_bounds__(256) void k_sg2(const int* __restrict__ row_ptr, const int* __restrict__ ssrc,
                                             const float* __restrict__ a2s, const float* __restrict__ a2d,
                                             const float* __restrict__ a2es, const u16* __restrict__ h2b,
                                             const float* __restrict__ bias, float* __restrict__ hfin) {
    __shared__ float wl[4][256];
    __shared__ int   sl[4][256];
    int t = threadIdx.x;
    int wv = t >> 6, L = t & 63;
    int n = blockIdx.x * 4 + wv;
    int beg = row_ptr[n], deg = row_ptr[n + 1] - beg;
    int lim = (deg < 256) ? deg : 256;
    {   // ---- phase 1 ----
        float adn = a2d[n];
        float m = -3.0e38f, s = 0.f;
        for (int i = L; i < deg; i += 64) {
            int pos = beg + i;
            int sv = ssrc[pos];
            if (i < 256) sl[wv][i] = sv;
            float l = a2s[sv] + adn + a2es[pos];
            l = (l > 0.f) ? l : 0.2f * l;
            if (i < 256) wl[wv][i] = l;
            if (l > m) { s = s * __expf(m - l) + 1.f; m = l; }
            else       { s += __expf(l - m); }
        }
        for (int o = 1; o < 64; o <<= 1) {
            float mo = __shfl_xor(m, o, 64), so = __shfl_xor(s, o, 64);
            float M = fmaxf(m, mo);
            s = s * __expf(m - M) + so * __expf(mo - M);
            m = M;
        }
        float inv = 1.f / (s + 1e-16f);
        for (int i = L; i < lim; i += 64)
            wl[wv][i] = __expf(wl[wv][i] - m) * inv;
    }
    asm volatile("" ::: "memory");
    __builtin_amdgcn_s_waitcnt(0);
    // ---- phase 2: pipelined ----
    int halfE = L >> 5;
    int L32 = L & 31;
    float a0 = 0.f, a1v = 0.f;
    const u32* h2u = (const u32*)h2b;
    u32 U[4];
    float W[4];
    #pragma unroll
    for (int k = 0; k < 4; k++) {
        int ii = 2 * k + halfE;
        bool v = ii < deg;
        int s = v ? sl[wv][ii] : 0;
        W[k] = v ? wl[wv][ii] : 0.f;
        U[k] = h2u[(size_t)s * 32 + L32];
    }
    for (int i = 0; i < deg; i += 8) {
        u32 C0 = U[0], C1 = U[1], C2 = U[2], C3 = U[3];
        float W0 = W[0], W1 = W[1], W2 = W[2], W3 = W[3];
        int ib = i + 8;
        #pragma unroll
        for (int k = 0; k < 4; k++) {
            int ii = ib + 2 * k + halfE;
            bool v = ii < deg;
            int s = v ? sl[wv][ii] : 0;
            W[k] = v ? wl[wv][ii] : 0.f;
            U[k] = h2u[(size_t)s * 32 + L32];
        }
        a0  += W0 * lo16(C0) + W1 * lo16(C1) + W2 * lo16(C2) + W3 * lo16(C3);
        a1v += W0 * hi16(C0) + W1 * hi16(C1) + W2 * hi16(C2) + W3 * hi16(C3);
    }
    a0  += __shfl_xor(a0, 32, 64);
    a1v += __shfl_xor(a1v, 32, 64);
    if (halfE == 0) {
        float2 o;
        o.x = a0  + bias[2 * L32];
        o.y = a1v + bias[2 * L32 + 1];
        *(float2*)(hfin + (size_t)n * 64 + 2 * L32) = o;
    }
}

// ---------- pooling + classifier ----------
__global__ __launch_bounds__(64) void k_pool(const int* __restrict__ bvec, const float* __restrict__ hf,
                                             const float* gateW, const float* gateb,
                                             const float* __restrict__ scene,
                                             const float* c1W, const float* c1b,
                                             const float* c2W, const float* c2b,
                                             float* __restrict__ outp) {
    int b = blockIdx.x, lane = threadIdx.x;
    __shared__ float gwl[64], se[64], comb[192], hid[64];
    gwl[lane] = gateW[lane];
    __syncthreads();
    int s0, s1;
    { int lo = 0, hi = N_NODES; while (lo < hi) { int mid = (lo + hi) >> 1; if (bvec[mid] < b) lo = mid + 1; else hi = mid; } s0 = lo; }
    { int lo = 0, hi = N_NODES; while (lo < hi) { int mid = (lo + hi) >> 1; if (bvec[mid] < b + 1) lo = mid + 1; else hi = mid; } s1 = lo; }
    float gb = gateb[0];
    float m = -3.0e38f, ssum = 0.f, acc = 0.f;
    for (int cs = s0; cs < s1; cs += 64) {
        int cnt = min(64, s1 - cs);
        float l = -3.0e38f;
        if (lane < cnt) {
            int n = cs + lane;
            float d = 0.f;
            for (int i = 0; i < 64; i++) d += hf[(size_t)n * 64 + i] * gwl[i];
            l = d + gb;
        }
        float cm = wmax(l);
        float newm = fmaxf(m, cm);
        float rsc = __expf(m - newm);
        float e = (lane < cnt) ? __expf(l - newm) : 0.f;
        float es = wsum(e);
        ssum = ssum * rsc + es;
        se[lane] = e;
        __syncthreads();
        float a2 = 0.f;
        for (int i = 0; i < cnt; i++) a2 += se[i] * hf[(size_t)(cs + i) * 64 + lane];
        acc = acc * rsc + a2;
        __syncthreads();
        m = newm;
    }
    float rel = acc / (ssum + 1e-16f);
    comb[lane] = scene[b * 128 + lane];
    comb[64 + lane] = scene[b * 128 + 64 + lane];
    comb[128 + lane] = rel;
    __syncthreads();
    float hj = 0.f;
    for (int k = 0; k < 192; k++) hj += comb[k] * c1W[k * 64 + lane];
    hj += c1b[lane];
    hid[lane] = fmaxf(hj, 0.f);
    __syncthreads();
    if (lane < 3) {
        float o = 0.f;
        for (int k = 0; k < 64; k++) o += hid[k] * c2W[k * 3 + lane];
        o += c2b[lane];
        outp[b * 3 + lane] = o;
    }
}

extern "C" void kernel_launch(void* const* d_in, const int* in_sizes, int n_in,
                              void* d_out, int out_size, void* d_ws, size_t ws_size,
                              hipStream_t stream) {
    (void)in_sizes; (void)n_in; (void)out_size; (void)ws_size;
    const float* gf     = (const float*)d_in[0];
    const float* x      = (const float*)d_in[1];
    const float* roi    = (const float*)d_in[2];
    const int*   ei     = (const int*)d_in[3];
    const float* ea     = (const float*)d_in[4];
    const int*   bvec   = (const int*)d_in[5];
    const float* roiW   = (const float*)d_in[6];
    const float* roib   = (const float*)d_in[7];
    const float* sceneW = (const float*)d_in[8];
    const float* sceneb = (const float*)d_in[9];
    const float* g1W    = (const float*)d_in[10];
    const float* g1as   = (const float*)d_in[11];
    const float* g1ad   = (const float*)d_in[12];
    const float* g1We   = (const float*)d_in[13];
    const float* g1ae   = (const float*)d_in[14];
    const float* g1b    = (const float*)d_in[15];
    const float* g2W    = (const float*)d_in[16];
    const float* g2as   = (const float*)d_in[17];
    const float* g2ad   = (const float*)d_in[18];
    const float* g2We   = (const float*)d_in[19];
    const float* g2ae   = (const float*)d_in[20];
    const float* g2b    = (const float*)d_in[21];
    const float* gateW  = (const float*)d_in[22];
    const float* gateb  = (const float*)d_in[23];
    const float* c1W    = (const float*)d_in[24];
    const float* c1b    = (const float*)d_in[25];
    const float* c2W    = (const float*)d_in[26];
    const float* c2b    = (const float*)d_in[27];

    char* w = (char*)d_ws;
    size_t o = 0;
    auto nxt = [&](size_t bytes) -> char* {
        char* p = w + o;
        o += (bytes + 255) & ~(size_t)255;
        return p;
    };
    float* scene  = (float*)nxt((size_t)NB * 128 * 4);
    float* M1     = (float*)nxt(80);
    float* M2     = (float*)nxt(32);
    u16* g1Wt     = (u16*)nxt((size_t)256 * 96 * 2);
    u16* roiWt    = (u16*)nxt((size_t)64 * 256 * 2);
    u16* g2Wt     = (u16*)nxt((size_t)64 * 256 * 2);
    int* cnt      = (int*)nxt((size_t)N_NODES * 4);
    int* pre      = (int*)nxt((size_t)N_NODES * 4);
    int* bsum     = (int*)nxt(64 * 4);
    int* row_ptr  = (int*)nxt((size_t)(N_NODES + 1) * 4);
    int* coarse   = (int*)nxt(256 * 4);
    u32* bpack    = (u32*)nxt((size_t)N_EDGES * 4);
    int* bsrc     = (int*)nxt((size_t)N_EDGES * 4);
    int* ssrc     = (int*)nxt((size_t)N_EDGES * 4);
    float* a1es   = (float*)nxt((size_t)N_EDGES * 16);
    float* a2es   = (float*)nxt((size_t)N_EDGES * 4);
    u16* visb     = (u16*)nxt((size_t)N_NODES * 64 * 2);
    u16* h1       = (u16*)nxt((size_t)N_NODES * 256 * 2);
    u16* out1     = (u16*)nxt((size_t)N_NODES * 256 * 2);
    u16* h2b      = (u16*)nxt((size_t)N_NODES * 64 * 2);
    float* hfin   = (float*)nxt((size_t)N_NODES * 64 * 4);
    float* a1s    = (float*)nxt((size_t)N_NODES * 16);
    float* a1d    = (float*)nxt((size_t)N_NODES * 16);
    float* a2s    = (float*)nxt((size_t)N_NODES * 4);
    float* a2d    = (float*)nxt((size_t)N_NODES * 4);

    hipMemsetAsync(cnt, 0, (size_t)N_NODES * 4, stream);
    k_wprep<<<113, 512, 0, stream>>>(g1W, roiW, g2W, g1We, g1ae, g2We, g2ae,
                                     g1Wt, roiWt, g2Wt, M1, M2);
    k_scene<<<(NB * 128) / 256, 256, 0, stream>>>(gf, sceneW, sceneb, scene);
    k_hist<<<N_EDGES / 256, 256, 0, stream>>>(ei, cnt);
    k_scan_blk<<<64, 256, 0, stream>>>(cnt, pre, bsum);
    k_scan_top<<<1, 64, 0, stream>>>(bsum);
    k_scan_fix<<<N_NODES / 256, 256, 0, stream>>>(pre, bsum, row_ptr, coarse);
    k_bucket<<<512, 256, 0, stream>>>(ei, coarse, bpack, bsrc);
    k_sortp<<<256, 256, 0, stream>>>(bpack, bsrc, row_ptr, ea, M1, M2, ssrc, a1es, a2es);
    k_vis<<<N_NODES / 64, 256, 0, stream>>>(roi, roiWt, roib, visb);
    k_h1<<<N_NODES / 64, 256, 0, stream>>>(x, visb, g1Wt, g1as, g1ad, h1, a1s, a1d);
    k_sg1<<<N_NODES / 4, 256, 0, stream>>>(row_ptr, ssrc, a1s, a1d, a1es, h1, g1b, out1);
    k_h2<<<N_NODES / 64, 256, 0, stream>>>(out1, g2Wt, g2as, g2ad, h2b, a2s, a2d);
    k_sg2<<<N_NODES / 4, 256, 0, stream>>>(row_ptr, ssrc, a2s, a2d, a2es, h2b, g2b, hfin);
    k_pool<<<NB, 64, 0, stream>>>(bvec, hfin, gateW, gateb, scene, c1W, c1b, c2W, c2b, (float*)d_out);
}